// Round 10
// baseline (962.585 us; speedup 1.0000x reference)
//
#include <hip/hip_runtime.h>

#define DEV __device__ __forceinline__

typedef short s16x8 __attribute__((ext_vector_type(8)));
typedef float f32x4 __attribute__((ext_vector_type(4)));
typedef __fp16 fp16x8 __attribute__((ext_vector_type(8)));
typedef unsigned short u16;
typedef unsigned long long u64;

constexpr int Wn = 128;    // words
constexpr int Pn = 4096;   // phrases
constexpr int Rn = 8192;   // relations
constexpr int Hn = 1024;   // hidden

DEV float b2f(u16 u) { union { unsigned i; float f; } x; x.i = (unsigned)u << 16; return x.f; }
DEV u16 f2b(float f) {
  union { float f; unsigned i; } x; x.f = f;
  unsigned r = x.i + 0x7FFF + ((x.i >> 16) & 1);   // RNE
  return (u16)(r >> 16);
}
DEV u16 f2h(float x) { __fp16 h = (__fp16)x; u16 r; __builtin_memcpy(&r, &h, 2); return r; }
DEV float leaky(float x) { return x >= 0.f ? x : 0.01f * x; }

DEV void load_lds16(const void* g, void* l) {
  __builtin_amdgcn_global_load_lds(
      (const __attribute__((address_space(1))) void*)g,
      (__attribute__((address_space(3))) void*)l, 16, 0, 0);
}

DEV float wred_sum(float v) {
  #pragma unroll
  for (int m = 1; m < 64; m <<= 1) v += __shfl_xor(v, m, 64);
  return v;
}
DEV float wred_max(float v) {
  #pragma unroll
  for (int m = 1; m < 64; m <<= 1) v = fmaxf(v, __shfl_xor(v, m, 64));
  return v;
}

// f32 -> bf16 row-block convert (8 elems/thread); rows are 1024 wide.
__global__ __launch_bounds__(256) void k_cvt(
    const float* __restrict__ src, int sld, u16* __restrict__ dst)
{
  int g = blockIdx.x * 256 + threadIdx.x;
  int row = g >> 7, c = (g & 127) * 8;
  const float* s = src + (size_t)row * sld + c;
  float4 a = *(const float4*)s;
  float4 b = *(const float4*)(s + 4);
  ushort4 lo = {f2b(a.x), f2b(a.y), f2b(a.z), f2b(a.w)};
  ushort4 hi = {f2b(b.x), f2b(b.y), f2b(b.z), f2b(b.w)};
  *(ushort4*)(dst + (size_t)row * 1024 + c) = lo;
  *(ushort4*)(dst + (size_t)row * 1024 + c + 4) = hi;
}

// ---------------------------------------------------------------------------
// 128x128 tile GEMM, 256 threads: C = epilogue(A[M,K] @ B[N,K]^T), bf16 in.
// ---------------------------------------------------------------------------
template<bool OUTF32, bool ACT, bool BIAS, bool RES, bool DUAL>
__global__ __launch_bounds__(256) void k_gemm_bt(
    const u16* __restrict__ A, int lda, const u16* __restrict__ B, int ldb,
    void* Cp, int ldc, const float* __restrict__ bias,
    const float* res, int ldr, u16* C16, float alpha, int K)
{
  __shared__ __align__(16) char sm[32768];
  char* As = sm;
  char* Bs = sm + 16384;
  const int tid = threadIdx.x;
  const int lane = tid & 63, w = tid >> 6;
  const int m0 = blockIdx.y * 128, n0 = blockIdx.x * 128;
  const int wr = (w >> 1) * 64, wc = (w & 1) * 64;
  const int r_lo = lane & 15, kq = lane >> 4;

  f32x4 acc[4][4];
  #pragma unroll
  for (int i = 0; i < 4; ++i)
    #pragma unroll
    for (int j = 0; j < 4; ++j) acc[i][j] = (f32x4){0.f, 0.f, 0.f, 0.f};

  for (int kt = 0; kt < K; kt += 64) {
    if (kt) __syncthreads();
    #pragma unroll
    for (int i = 0; i < 4; ++i) {
      int f = i * 4096 + tid * 16;
      int row = f >> 7, colb = f & 127;
      int scol = colb ^ ((row & 7) << 4);
      load_lds16((const char*)(A + (size_t)(m0 + row) * lda + kt) + scol,
                 As + i * 4096 + w * 1024);
    }
    #pragma unroll
    for (int i = 0; i < 4; ++i) {
      int f = i * 4096 + tid * 16;
      int row = f >> 7, colb = f & 127;
      int scol = colb ^ ((row & 7) << 4);
      load_lds16((const char*)(B + (size_t)(n0 + row) * ldb + kt) + scol,
                 Bs + i * 4096 + w * 1024);
    }
    __syncthreads();
    #pragma unroll
    for (int ks = 0; ks < 2; ++ks) {
      s16x8 af[4], bfr[4];
      const int kb = ks * 64 + kq * 16;
      #pragma unroll
      for (int mi = 0; mi < 4; ++mi) {
        int row = wr + mi * 16 + r_lo;
        af[mi] = *(const s16x8*)(As + row * 128 + (kb ^ ((row & 7) << 4)));
      }
      #pragma unroll
      for (int ni = 0; ni < 4; ++ni) {
        int row = wc + ni * 16 + r_lo;
        bfr[ni] = *(const s16x8*)(Bs + row * 128 + (kb ^ ((row & 7) << 4)));
      }
      #pragma unroll
      for (int mi = 0; mi < 4; ++mi)
        #pragma unroll
        for (int ni = 0; ni < 4; ++ni)
          acc[mi][ni] = __builtin_amdgcn_mfma_f32_16x16x32_bf16(af[mi], bfr[ni], acc[mi][ni], 0, 0, 0);
    }
  }
  #pragma unroll
  for (int mi = 0; mi < 4; ++mi)
    #pragma unroll
    for (int ni = 0; ni < 4; ++ni)
      #pragma unroll
      for (int j = 0; j < 4; ++j) {
        int r = m0 + wr + mi * 16 + kq * 4 + j;
        int c = n0 + wc + ni * 16 + r_lo;
        float v = acc[mi][ni][j] * alpha;
        if (BIAS) v += bias[c];
        if (RES)  v += res[(size_t)r * ldr + c];
        if (ACT)  v = leaky(v);
        if (OUTF32) ((float*)Cp)[(size_t)r * ldc + c] = v;
        else        ((u16*)Cp)[(size_t)r * ldc + c] = f2b(v);
        if (DUAL)   C16[(size_t)r * ldc + c] = f2b(v);
      }
}

// ---------------------------------------------------------------------------
// Fused relation GEMM: C[4096x1024] += [upd16[sub[r]] | upd16[obj[r]]] @
// [W1 | W2]^T  (K=2048, A rows gathered during LDS staging, C f32 in-place).
// ---------------------------------------------------------------------------
__global__ __launch_bounds__(256) void k_gemm_rel(
    const u16* __restrict__ upd16, const int* __restrict__ sub,
    const int* __restrict__ obj, const u16* __restrict__ W1,
    const u16* __restrict__ W2, float* __restrict__ C)
{
  __shared__ __align__(16) char sm[32768];
  __shared__ int ridx[2][128];
  char* As = sm;
  char* Bs = sm + 16384;
  const int tid = threadIdx.x;
  const int lane = tid & 63, w = tid >> 6;
  const int m0 = blockIdx.y * 128, n0 = blockIdx.x * 128;
  const int wr = (w >> 1) * 64, wc = (w & 1) * 64;
  const int r_lo = lane & 15, kq = lane >> 4;

  if (tid < 128) ridx[0][tid] = sub[m0 + tid];
  else if (tid < 256) ridx[1][tid - 128] = obj[m0 + tid - 128];
  __syncthreads();

  f32x4 acc[4][4];
  #pragma unroll
  for (int i = 0; i < 4; ++i)
    #pragma unroll
    for (int j = 0; j < 4; ++j) acc[i][j] = (f32x4){0.f, 0.f, 0.f, 0.f};

  for (int kt = 0; kt < 2048; kt += 64) {
    const int half = kt >> 10;
    const int kk = kt & 1023;
    const u16* Wm = half ? W2 : W1;
    __syncthreads();
    #pragma unroll
    for (int i = 0; i < 4; ++i) {        // stage A (gathered rows)
      int f = i * 4096 + tid * 16;
      int row = f >> 7, colb = f & 127;
      int scol = colb ^ ((row & 7) << 4);
      load_lds16((const char*)(upd16 + (size_t)ridx[half][row] * 1024 + kk) + scol,
                 As + i * 4096 + w * 1024);
    }
    #pragma unroll
    for (int i = 0; i < 4; ++i) {        // stage B
      int f = i * 4096 + tid * 16;
      int row = f >> 7, colb = f & 127;
      int scol = colb ^ ((row & 7) << 4);
      load_lds16((const char*)(Wm + (size_t)(n0 + row) * 1024 + kk) + scol,
                 Bs + i * 4096 + w * 1024);
    }
    __syncthreads();
    #pragma unroll
    for (int ks = 0; ks < 2; ++ks) {
      s16x8 af[4], bfr[4];
      const int kb = ks * 64 + kq * 16;
      #pragma unroll
      for (int mi = 0; mi < 4; ++mi) {
        int row = wr + mi * 16 + r_lo;
        af[mi] = *(const s16x8*)(As + row * 128 + (kb ^ ((row & 7) << 4)));
      }
      #pragma unroll
      for (int ni = 0; ni < 4; ++ni) {
        int row = wc + ni * 16 + r_lo;
        bfr[ni] = *(const s16x8*)(Bs + row * 128 + (kb ^ ((row & 7) << 4)));
      }
      #pragma unroll
      for (int mi = 0; mi < 4; ++mi)
        #pragma unroll
        for (int ni = 0; ni < 4; ++ni)
          acc[mi][ni] = __builtin_amdgcn_mfma_f32_16x16x32_bf16(af[mi], bfr[ni], acc[mi][ni], 0, 0, 0);
    }
  }
  #pragma unroll
  for (int mi = 0; mi < 4; ++mi)
    #pragma unroll
    for (int ni = 0; ni < 4; ++ni)
      #pragma unroll
      for (int j = 0; j < 4; ++j) {
        int r = m0 + wr + mi * 16 + kq * 4 + j;
        int c = n0 + wc + ni * 16 + r_lo;
        C[(size_t)r * Hn + c] = acc[mi][ni][j] + C[(size_t)r * Hn + c];
      }
}

// ---------------------------------------------------------------------------
// MEGA: GRU blocks placed XCD-locally (HW dispatch ~ bid%8): dir 0 = blocks
// bid%8==0 slots 0..15 (all XCD 0), dir 1 = bid%8==1 (XCD 1) -> the per-step
// h exchange stays within one XCD's L2. Other 224 blocks: cvt task list.
// GRU per step: gh[96] = W@h via MFMA matvec (no cross-lane reduces);
// packed f16 u64 exchange + single RELEASE counter.
// ---------------------------------------------------------------------------
struct CvtTask { const float* src; u16* dst; int sld; int units; };
struct MKArgs {
  const float *w_hh_f, *w_hh_b, *b_hh_f, *b_hh_b;
  const float *gi_f, *gi_b;
  u64* X; int* cntX; float* ctx;
  CvtTask t[10]; int nt;
};

__global__ __launch_bounds__(256) void k_mega(MKArgs a)
{
  __shared__ __align__(16) u16 wlds[96 * 512];   // 96KB f16 weights, swizzled
  __shared__ float bh[96];
  __shared__ float partg[4][96];
  __shared__ __align__(16) u16 hb[512];          // h as f16 bits

  const int bid = blockIdx.x;
  const int tid = threadIdx.x;
  const int lane = tid & 63, wv = tid >> 6;
  const int xcd = bid & 7, slot = bid >> 3;
  const bool isGru = (xcd < 2) && (slot < 16);

  if (!isGru) {                          // ---- conversion workers ----
    int before = (slot < 16) ? (slot * 2 + (xcd < 2 ? xcd : 2)) : 32;
    int bc = bid - before;
    int nb = (int)gridDim.x - 32;
    for (int k = 0; k < a.nt; ++k) {
      const float* src = a.t[k].src;
      u16* dst = a.t[k].dst;
      int sld = a.t[k].sld;
      int units = a.t[k].units;
      for (int u = bc * 256 + tid; u < units; u += nb * 256) {
        int row = u >> 7, c = (u & 127) * 8;
        const float* s = src + (size_t)row * sld + c;
        float4 va = *(const float4*)s;
        float4 vb = *(const float4*)(s + 4);
        ushort4 lo = {f2b(va.x), f2b(va.y), f2b(va.z), f2b(va.w)};
        ushort4 hi = {f2b(vb.x), f2b(vb.y), f2b(vb.z), f2b(vb.w)};
        *(ushort4*)(dst + (size_t)row * 1024 + c) = lo;
        *(ushort4*)(dst + (size_t)row * 1024 + c + 4) = hi;
      }
    }
    return;
  }

  // ---- GRU ----
  const int dir = xcd;
  const int b   = slot;
  const float* w_hh = dir ? a.w_hh_b : a.w_hh_f;
  const float* b_hhp = dir ? a.b_hh_b : a.b_hh_f;
  const float* gi = dir ? a.gi_b : a.gi_f;
  u64* Xd = a.X + (size_t)dir * 128 * 128;
  int* cntD = a.cntX + dir * 128;

  // weights f32 -> f16 LDS, row-major 1KB rows, byte ^ ((row&7)<<4) swizzle
  for (int idx = tid; idx < 96 * 128; idx += 256) {
    int gl = idx >> 7;
    int kc = (idx & 127) << 2;          // element index (x4 floats)
    int g  = 32 * b + (gl & 31) + ((gl >> 5) << 9);
    float4 wv4 = *(const float4*)(w_hh + (size_t)g * 512 + kc);
    u16 d4[4] = {f2h(wv4.x), f2h(wv4.y), f2h(wv4.z), f2h(wv4.w)};
    int byte = (kc * 2) ^ ((gl & 7) << 4);
    *(uint2*)((char*)wlds + gl * 1024 + byte) = *(uint2*)d4;
  }
  if (tid < 96) {
    int g = 32 * b + (tid & 31) + ((tid >> 5) << 9);
    bh[tid] = b_hhp[g];
  }
  for (int i = tid; i < 256; i += 256) ((unsigned*)hb)[i] = 0u;
  __syncthreads();

  float hprev = 0.f;
  const int jg = 32 * b + tid;          // tid<32 meaningful
  const int r_lo = lane & 15, kq = lane >> 4;
  const fp16x8 zf = {0, 0, 0, 0, 0, 0, 0, 0};

  for (int sidx = 0; sidx < 128; ++sidx) {
    const int t = dir ? (127 - sidx) : sidx;

    float gir = 0.f, giz = 0.f, gin = 0.f;
    if (tid < 32) {                     // prefetch under MFMA phase
      gir = gi[t * 1536 + jg];
      giz = gi[t * 1536 + 512 + jg];
      gin = gi[t * 1536 + 1024 + jg];
    }

    // MFMA matvec: wave wv covers K-tiles wv*4..wv*4+3, all 6 gate-tiles
    f32x4 acc6[6];
    #pragma unroll
    for (int gt = 0; gt < 6; ++gt) acc6[gt] = (f32x4){0.f, 0.f, 0.f, 0.f};
    #pragma unroll
    for (int k2 = 0; k2 < 4; ++k2) {
      int kt = (wv << 2) + k2;
      fp16x8 bf = (r_lo == 0) ? *(const fp16x8*)(hb + kt * 32 + kq * 8) : zf;
      #pragma unroll
      for (int gt = 0; gt < 6; ++gt) {
        int gl = gt * 16 + r_lo;
        int byte = (kt * 64 + kq * 16) ^ ((gl & 7) << 4);
        fp16x8 af = *(const fp16x8*)((const char*)wlds + gl * 1024 + byte);
        acc6[gt] = __builtin_amdgcn_mfma_f32_16x16x32_f16(af, bf, acc6[gt], 0, 0, 0);
      }
    }
    if (r_lo == 0) {                    // col-0 lanes: rows kq*4+j
      #pragma unroll
      for (int gt = 0; gt < 6; ++gt)
        #pragma unroll
        for (int j = 0; j < 4; ++j)
          partg[wv][gt * 16 + kq * 4 + j] = acc6[gt][j];
    }
    __syncthreads();

    if (wv == 0) {
      float h2v = 0.f;
      if (lane < 32) {
        int j = lane;
        float ghr = partg[0][j] + partg[1][j] + partg[2][j] + partg[3][j] + bh[j];
        float ghz = partg[0][j + 32] + partg[1][j + 32] + partg[2][j + 32] + partg[3][j + 32] + bh[j + 32];
        float ghn = partg[0][j + 64] + partg[1][j + 64] + partg[2][j + 64] + partg[3][j + 64] + bh[j + 64];
        float rr = 1.f / (1.f + __expf(-(gir + ghr)));
        float zz = 1.f / (1.f + __expf(-(giz + ghz)));
        float nn = tanhf(gin + rr * ghn);
        h2v = (1.f - zz) * nn + zz * hprev;
        hprev = h2v;
        if (sidx == 0)   a.ctx[(dir ? 1536 : 0)    + jg] = h2v;
        if (sidx == 127) a.ctx[(dir ? 512  : 1024) + jg] = h2v;
      }
      if (sidx < 127) {
        int l4 = (lane & 7) * 4;        // pack 4 h into one u64
        float p0 = __shfl(h2v, l4 + 0, 64);
        float p1 = __shfl(h2v, l4 + 1, 64);
        float p2 = __shfl(h2v, l4 + 2, 64);
        float p3 = __shfl(h2v, l4 + 3, 64);
        if (lane < 8) {
          u64 pk = (u64)f2h(p0) | ((u64)f2h(p1) << 16) |
                   ((u64)f2h(p2) << 32) | ((u64)f2h(p3) << 48);
          __hip_atomic_store(&Xd[(size_t)sidx * 128 + b * 8 + lane], pk,
                             __ATOMIC_RELAXED, __HIP_MEMORY_SCOPE_AGENT);
        }
        if (lane == 0)
          __hip_atomic_fetch_add(&cntD[sidx], 1, __ATOMIC_RELEASE,
                                 __HIP_MEMORY_SCOPE_AGENT);
        // poll one word, then batch-load the 1KB h vector
        while (__hip_atomic_load(&cntD[sidx], __ATOMIC_ACQUIRE,
                                 __HIP_MEMORY_SCOPE_AGENT) < 16)
          __builtin_amdgcn_s_sleep(1);
        const u64* src = Xd + (size_t)sidx * 128;
        u64 w0 = __hip_atomic_load(&src[2 * lane],     __ATOMIC_RELAXED, __HIP_MEMORY_SCOPE_AGENT);
        u64 w1 = __hip_atomic_load(&src[2 * lane + 1], __ATOMIC_RELAXED, __HIP_MEMORY_SCOPE_AGENT);
        *(u64*)(hb + lane * 8)     = w0;
        *(u64*)(hb + lane * 8 + 4) = w1;
      }
    }
    __syncthreads();                    // hb ready for all waves
  }
}

// ---------------------------------------------------------------------------
// small kernels
// ---------------------------------------------------------------------------
__global__ __launch_bounds__(256) void k_softmax1(
    const float* __restrict__ scores, const int* __restrict__ conn, u16* __restrict__ attw)
{
  int p = blockIdx.x * 4 + (threadIdx.x >> 6);
  int lane = threadIdx.x & 63;
  float v0 = scores[(size_t)p * 128 + lane];
  float v1 = scores[(size_t)p * 128 + 64 + lane];
  int m0 = conn[(size_t)p * 128 + lane];
  int m1 = conn[(size_t)p * 128 + 64 + lane];
  float x0 = m0 > 0 ? v0 : -INFINITY;
  float x1 = m1 > 0 ? v1 : -INFINITY;
  float mx = wred_max(fmaxf(x0, x1));
  if (!(mx > -INFINITY)) mx = 0.f;
  float e0 = m0 > 0 ? __expf(v0 - mx) : 0.f;
  float e1 = m1 > 0 ? __expf(v1 - mx) : 0.f;
  float s = wred_sum(e0 + e1);
  float inv = 1.f / (s + 1e-6f);
  attw[(size_t)p * 128 + lane] = f2b(e0 * inv);
  attw[(size_t)p * 128 + 64 + lane] = f2b(e1 * inv);
}

__global__ __launch_bounds__(256) void k_transpose(const u16* __restrict__ in, u16* __restrict__ out)
{
  int idx = blockIdx.x * 256 + threadIdx.x;   // over 128*1024
  int r = idx >> 10, c = idx & 1023;
  out[c * 128 + r] = in[idx];
}

__global__ __launch_bounds__(256) void k_cvec(const float* __restrict__ att1W,
    const float* __restrict__ att1b, const float* __restrict__ ctx, float* __restrict__ cvec)
{
  int i = blockIdx.x * 4 + (threadIdx.x >> 6);
  int lane = threadIdx.x & 63;
  const float* wrow = att1W + (size_t)i * 4096 + 2048 + lane * 32;
  const float* cp = ctx + lane * 32;
  float acc = 0.f;
  #pragma unroll
  for (int k = 0; k < 32; ++k) acc += wrow[k] * cp[k];
  acc = wred_sum(acc);
  if (lane == 0) cvec[i] = acc + att1b[i];
}

__global__ __launch_bounds__(256) void k_edge_s(const int* __restrict__ rcm,
    const u16* __restrict__ U1, const u16* __restrict__ V1, const float* __restrict__ cvec,
    const float* __restrict__ att2w, const float* __restrict__ att2b,
    float* __restrict__ sval)
{
  int idx = blockIdx.x * 4 + (threadIdx.x >> 6);   // [0, 2*Rn)
  int lane = threadIdx.x & 63;
  int rL = idx < Rn ? idx : idx - Rn;
  int p = rcm[idx];
  const u16* u = U1 + (size_t)p * Hn + lane * 16;
  const u16* v = V1 + (size_t)rL * Hn + lane * 16;
  const float* aw = att2w + lane * 16;
  const float* cv = cvec + lane * 16;
  float acc = 0.f;
  #pragma unroll
  for (int i = 0; i < 16; ++i) {
    float x = b2f(u[i]) + b2f(v[i]) + cv[i];
    acc += aw[i] * leaky(x);
  }
  acc = wred_sum(acc);
  if (lane == 0) sval[idx] = acc + att2b[0];
}

__global__ __launch_bounds__(256) void k_cnt(const int* __restrict__ rcm, int* __restrict__ cnt)
{
  int e = blockIdx.x * 256 + threadIdx.x;
  if (e < Rn && rcm[e] == rcm[Rn + e]) return;   // duplicate cell: obj wins
  atomicAdd(cnt + rcm[e], 1);
}

__global__ __launch_bounds__(256) void k_scan(const int* __restrict__ cnt,
    int* __restrict__ offs, int* __restrict__ cursor)
{
  __shared__ int part[256];
  __shared__ int pscan[256];
  int tid = threadIdx.x;
  int loc[16]; int s = 0;
  #pragma unroll
  for (int i = 0; i < 16; ++i) { loc[i] = cnt[tid * 16 + i]; s += loc[i]; }
  part[tid] = s; __syncthreads();
  if (tid == 0) { int a = 0; for (int i = 0; i < 256; ++i) { pscan[i] = a; a += part[i]; } }
  __syncthreads();
  int base = pscan[tid];
  #pragma unroll
  for (int i = 0; i < 16; ++i) { offs[tid * 16 + i] = base; cursor[tid * 16 + i] = base; base += loc[i]; }
  if (tid == 255) offs[Pn] = base;
}

__global__ __launch_bounds__(256) void k_fill(const int* __restrict__ rcm,
    const float* __restrict__ sval, int* __restrict__ cursor,
    int* __restrict__ er, float* __restrict__ es)
{
  int e = blockIdx.x * 256 + threadIdx.x;
  if (e < Rn && rcm[e] == rcm[Rn + e]) return;
  int slot = atomicAdd(cursor + rcm[e], 1);
  er[slot] = e & (Rn - 1);
  es[slot] = sval[e];
}

__global__ __launch_bounds__(256) void k_att_apply(const int* __restrict__ offs,
    const int* __restrict__ er, const float* __restrict__ es,
    const float* __restrict__ urel, u16* __restrict__ pacc)
{
  int p = blockIdx.x;
  int tid = threadIdx.x;
  int beg = offs[p], end = offs[p + 1];
  float mx = -INFINITY;
  for (int i = beg; i < end; ++i) mx = fmaxf(mx, es[i]);
  float den = 1e-6f;
  for (int i = beg; i < end; ++i) den += __expf(es[i] - mx);
  float inv = 1.f / den;
  float a0 = 0.f, a1 = 0.f, a2 = 0.f, a3 = 0.f;
  int c0 = tid * 4;
  for (int i = beg; i < end; ++i) {
    float wgt = __expf(es[i] - mx) * inv;
    float4 q = *(const float4*)(urel + (size_t)er[i] * Hn + c0);
    a0 += wgt * q.x; a1 += wgt * q.y; a2 += wgt * q.z; a3 += wgt * q.w;
  }
  ushort4 ov; ov.x = f2b(a0); ov.y = f2b(a1); ov.z = f2b(a2); ov.w = f2b(a3);
  *(ushort4*)(pacc + (size_t)p * Hn + c0) = ov;
}

// ---------------------------------------------------------------------------
extern "C" void kernel_launch(void* const* d_in, const int* in_sizes, int n_in,
                              void* d_out, int out_size, void* d_ws, size_t ws_size,
                              hipStream_t stream)
{
  const float* word_feat   = (const float*)d_in[0];
  const float* phrase_feat = (const float*)d_in[1];
  const float* rel_feat    = (const float*)d_in[2];
  const float* w_ih_f = (const float*)d_in[3];
  const float* w_hh_f = (const float*)d_in[4];
  const float* b_ih_f = (const float*)d_in[5];
  const float* b_hh_f = (const float*)d_in[6];
  const float* w_ih_b = (const float*)d_in[7];
  const float* w_hh_b = (const float*)d_in[8];
  const float* b_ih_b = (const float*)d_in[9];
  const float* b_hh_b = (const float*)d_in[10];
  const float* w2p_w_W = (const float*)d_in[11];
  const float* w2p_w_b = (const float*)d_in[12];
  const float* w2p_p_W = (const float*)d_in[13];
  const float* w2p_p_b = (const float*)d_in[14];
  const float* w2p_t_W = (const float*)d_in[15];
  const float* w2p_t_b = (const float*)d_in[16];
  const float* rel_W   = (const float*)d_in[17];
  const float* rel_b   = (const float*)d_in[18];
  const float* att1_W  = (const float*)d_in[19];
  const float* att1_b  = (const float*)d_in[20];
  const float* att2_W  = (const float*)d_in[21];
  const float* att2_b  = (const float*)d_in[22];
  const float* r2p_t_W = (const float*)d_in[23];
  const float* r2p_t_b = (const float*)d_in[24];
  const int* rcm  = (const int*)d_in[25];
  const int* conn = (const int*)d_in[26];

  float* out_word = (float*)d_out;
  float* out_phr  = out_word + (size_t)Wn * Hn;   // 4096x1024 f32
  float* out_urel = out_phr + (size_t)Pn * Hn;    // 8192x1024 f32

  // ---- workspace (~44.5 MB, proven layout) ----
  char* ws = (char*)d_ws;
  size_t off = 0;
  auto alloc = [&](size_t bytes) -> char* {
    char* pptr = ws + off; off += (bytes + 255) & ~(size_t)255; return pptr;
  };
  int*   cnt2   = (int*)alloc(Pn * 4);                    // } zeroed together
  int*   cntX   = (int*)alloc(256 * 4);                   // }
  u64*   X      = (u64*)alloc(2 * 128 * 128 * 8);         // } 256KB packed h
  size_t zlen   = Pn * 4 + 1024 + 2 * 128 * 128 * 8;
  float* ctx    = (float*)alloc(2048 * 4);
  float* cvec   = (float*)alloc(1024 * 4);
  int*   cursor = (int*)alloc(Pn * 4);
  int*   offs   = (int*)alloc((Pn + 1) * 4);
  int*   er     = (int*)alloc(2 * Rn * 4);
  float* es     = (float*)alloc(2 * Rn * 4);
  float* sval   = (float*)alloc(2 * Rn * 4);
  float* gi_f   = (float*)alloc(128 * 1536 * 4);
  float* gi_b   = (float*)alloc(128 * 1536 * 4);
  u16*   wf16   = (u16*)alloc((size_t)Wn * Hn * 2);
  u16*   wl     = (u16*)alloc((size_t)Wn * Hn * 2);
  u16*   upd16  = (u16*)alloc((size_t)Pn * Hn * 2);       // later: pacc
  char*  RA     = alloc(16777216);                        // W1s/W2s/W3s/G -> V1f
  u16*   W1s    = (u16*)RA;
  u16*   W2s    = (u16*)(RA + 2097152);
  u16*   W3s    = (u16*)(RA + 4194304);
  u16*   G      = (u16*)(RA + 6291456);                   // 8.39MB
  u16*   V1f    = (u16*)RA;                               // 16.78MB (late)
  u16*   A1p16  = (u16*)alloc(2097152);
  u16*   A1r16  = (u16*)alloc(2097152);
  u16*   U1     = (u16*)alloc((size_t)Pn * Hn * 2);
  char*  CBr    = alloc(4194304);                         // urel cvt chunk
  u16*   CB     = (u16*)CBr;
  u16*   r2pW16 = (u16*)CBr;                              // after CB dead
  u16*   pacc   = upd16;                                  // after U1 GEMM done

  // ---- d_out regions as early scratch ----
  char* phrB = (char*)out_phr;
  u16*   wih16f = (u16*)phrB;                           // 3.15MB
  u16*   wih16b = (u16*)(phrB + 3145728);               // 3.15MB
  float* scores = (float*)(phrB + 6291456);             // 2.10MB
  char* urlB = (char*)out_urel;
  u16*   pf16   = (u16*)urlB;                           // 8.39MB
  u16*   w2pw16 = (u16*)(urlB + 8388608);
  u16*   w2pp16 = (u16*)(urlB + 10485760);
  u16*   w2pt16 = (u16*)(urlB + 12582912);
  u16*   pl     = (u16*)(urlB + 14680064);              // 8.39MB
  u16*   aw     = (u16*)(urlB + 23068672);              // 8.39MB
  u16*   attw   = (u16*)(urlB + 31457280);              // 1.05MB
  u16*   wfT    = (u16*)(urlB + 32505856);              // 0.26MB

  (void)hipMemsetAsync(cnt2, 0, zlen, stream);

  dim3 blk(256);

  // prelaunch: wf16/wih cvts + gi GEMMs at full occupancy, cnt/scan early
  k_cvt<<<64, blk, 0, stream>>>(word_feat, Hn, wf16);
  k_cvt<<<768, blk, 0, stream>>>(w_ih_f, Hn, wih16f);
  k_cvt<<<768, blk, 0, stream>>>(w_ih_b, Hn, wih16b);
  k_gemm_bt<true, false, true, false, false><<<dim3(12, 1), blk, 0, stream>>>(
      wf16, Hn, wih16f, Hn, gi_f, 1536, b_ih_f, nullptr, 0, nullptr, 1.f, Hn);
  k_gemm_bt<true, false, true, false, false><<<dim3(12, 1), blk, 0, stream>>>(
      wf16, Hn, wih16b, Hn, gi_b, 1536, b_ih_b, nullptr, 0, nullptr, 1.f, Hn);
  k_cnt<<<(2 * Rn) / 256, blk, 0, stream>>>(rcm, cnt2);
  k_scan<<<1, blk, 0, stream>>>(cnt2, offs, cursor);

  // mega: GRU (XCD-local exchange) || bulk conversions
  MKArgs A;
  A.w_hh_f = w_hh_f; A.w_hh_b = w_hh_b; A.b_hh_f = b_hh_f; A.b_hh_b = b_hh_b;
  A.gi_f = gi_f; A.gi_b = gi_b; A.X = X; A.cntX = cntX; A.ctx = ctx;
  A.t[0] = {phrase_feat,    pf16,   Hn,     Pn * 128};
  A.t[1] = {w2p_w_W,        w2pw16, Hn,     1024 * 128};
  A.t[2] = {w2p_p_W,        w2pp16, Hn,     1024 * 128};
  A.t[3] = {w2p_t_W,        w2pt16, Hn,     1024 * 128};
  A.t[4] = {rel_W,          W1s,    3 * Hn, 1024 * 128};
  A.t[5] = {rel_W + Hn,     W2s,    3 * Hn, 1024 * 128};
  A.t[6] = {rel_W + 2 * Hn, W3s,    3 * Hn, 1024 * 128};
  A.t[7] = {att1_W,         A1p16,  4 * Hn, 1024 * 128};
  A.t[8] = {att1_W + Hn,    A1r16,  4 * Hn, 1024 * 128};
  A.t[9] = {rel_feat,       G,      Hn,     4096 * 128};   // rel lower half
  A.nt = 10;
  k_mega<<<256, blk, 0, stream>>>(A);
  k_cvec<<<256, blk, 0, stream>>>(att1_W, att1_b, ctx, cvec);

  // word->phrase attention; upd (f32 in out_phr + bf16 copy)
  k_gemm_bt<false, true, true, false, false><<<dim3(8, 1), blk, 0, stream>>>(
      wf16, Hn, w2pw16, Hn, wl, Hn, w2p_w_b, nullptr, 0, nullptr, 1.f, Hn);
  k_gemm_bt<false, true, true, false, false><<<dim3(8, 32), blk, 0, stream>>>(
      pf16, Hn, w2pp16, Hn, pl, Hn, w2p_p_b, nullptr, 0, nullptr, 1.f, Hn);
  k_gemm_bt<true, false, false, false, false><<<dim3(1, 32), blk, 0, stream>>>(
      pl, Hn, wl, Hn, scores, Wn, nullptr, nullptr, 0, nullptr, 0.03125f, Hn);
  k_softmax1<<<Pn / 4, blk, 0, stream>>>(scores, conn, attw);
  k_transpose<<<(Wn * Hn) / 256, blk, 0, stream>>>(wf16, wfT);
  k_gemm_bt<false, false, false, false, false><<<dim3(8, 32), blk, 0, stream>>>(
      attw, Wn, wfT, Wn, aw, Hn, nullptr, nullptr, 0, nullptr, 1.f, Wn);
  k_gemm_bt<true, false, true, true, true><<<dim3(8, 32), blk, 0, stream>>>(
      aw, Hn, w2pt16, Hn, out_phr, Hn, w2p_t_b, phrase_feat, Hn, upd16, 1.f, Hn);

  // urel: RF3 then fused dual-gather K=2048 accumulate per half
  k_gemm_bt<true, false, true, false, false><<<dim3(8, 32), blk, 0, stream>>>(
      G, Hn, W3s, Hn, out_urel, Hn, rel_b, nullptr, 0, nullptr, 1.f, Hn);
  k_cvt<<<2048, blk, 0, stream>>>(rel_feat + (size_t)4096 * Hn, Hn, G);
  k_gemm_bt<true, false, true, false, false><<<dim3(8, 32), blk, 0, stream>>>(
      G, Hn, W3s, Hn, out_urel + (size_t)4096 * Hn, Hn, rel_b, nullptr, 0,
      nullptr, 1.f, Hn);
  for (int h = 0; h < 2; ++h) {
    k_gemm_rel<<<dim3(8, 32), blk, 0, stream>>>(
        upd16, rcm + h * 4096, rcm + Rn + h * 4096, W1s, W2s,
        out_urel + (size_t)h * 4096 * Hn);
  }

  // U1 then V1 (4 chunks of 2048 rows into V1f over RA)
  k_gemm_bt<false, false, false, false, false><<<dim3(8, 32), blk, 0, stream>>>(
      upd16, Hn, A1p16, Hn, U1, Hn, nullptr, nullptr, 0, nullptr, 1.f, Hn);
  for (int cb = 0; cb < Rn; cb += 2048) {
    k_cvt<<<1024, blk, 0, stream>>>(out_urel + (size_t)cb * Hn, Hn, CB);
    k_gemm_bt<false, false, false, false, false><<<dim3(8, 16), blk, 0, stream>>>(
        CB, Hn, A1r16, Hn, V1f + (size_t)cb * Hn, Hn, nullptr, nullptr, 0,
        nullptr, 1.f, Hn);
  }
  k_cvt<<<512, blk, 0, stream>>>(r2p_t_W, Hn, r2pW16);   // CB dead now

  // edge scores + CSR softmax + att@urel + final residual GEMM
  k_edge_s<<<(2 * Rn) / 4, blk, 0, stream>>>(rcm, U1, V1f, cvec, att2_W, att2_b, sval);
  k_fill<<<(2 * Rn) / 256, blk, 0, stream>>>(rcm, sval, cursor, er, es);
  k_att_apply<<<Pn, blk, 0, stream>>>(offs, er, es, out_urel, pacc);
  k_gemm_bt<true, false, true, true, false><<<dim3(8, 32), blk, 0, stream>>>(
      pacc, Hn, r2pW16, Hn, out_phr, Hn, r2p_t_b, out_phr, Hn, nullptr, 1.f, Hn);

  (void)hipMemcpyAsync(out_word, word_feat, (size_t)Wn * Hn * 4,
                       hipMemcpyDeviceToDevice, stream);
}

// Round 11
// 798.094 us; speedup vs baseline: 1.2061x; 1.2061x over previous
//
#include <hip/hip_runtime.h>

#define DEV __device__ __forceinline__

typedef short s16x8 __attribute__((ext_vector_type(8)));
typedef float f32x4 __attribute__((ext_vector_type(4)));
typedef __fp16 fp16x8 __attribute__((ext_vector_type(8)));
typedef unsigned short u16;
typedef unsigned long long u64;

constexpr int Wn = 128;    // words
constexpr int Pn = 4096;   // phrases
constexpr int Rn = 8192;   // relations
constexpr int Hn = 1024;   // hidden

DEV float b2f(u16 u) { union { unsigned i; float f; } x; x.i = (unsigned)u << 16; return x.f; }
DEV u16 f2b(float f) {
  union { float f; unsigned i; } x; x.f = f;
  unsigned r = x.i + 0x7FFF + ((x.i >> 16) & 1);   // RNE
  return (u16)(r >> 16);
}
DEV u16 f2h(float x) { __fp16 h = (__fp16)x; u16 r; __builtin_memcpy(&r, &h, 2); return r; }
DEV float leaky(float x) { return x >= 0.f ? x : 0.01f * x; }

DEV void load_lds16(const void* g, void* l) {
  __builtin_amdgcn_global_load_lds(
      (const __attribute__((address_space(1))) void*)g,
      (__attribute__((address_space(3))) void*)l, 16, 0, 0);
}

DEV float wred_sum(float v) {
  #pragma unroll
  for (int m = 1; m < 64; m <<= 1) v += __shfl_xor(v, m, 64);
  return v;
}
DEV float wred_max(float v) {
  #pragma unroll
  for (int m = 1; m < 64; m <<= 1) v = fmaxf(v, __shfl_xor(v, m, 64));
  return v;
}

// f32 -> bf16 row-block convert (8 elems/thread); rows are 1024 wide.
__global__ __launch_bounds__(256) void k_cvt(
    const float* __restrict__ src, int sld, u16* __restrict__ dst)
{
  int g = blockIdx.x * 256 + threadIdx.x;
  int row = g >> 7, c = (g & 127) * 8;
  const float* s = src + (size_t)row * sld + c;
  float4 a = *(const float4*)s;
  float4 b = *(const float4*)(s + 4);
  ushort4 lo = {f2b(a.x), f2b(a.y), f2b(a.z), f2b(a.w)};
  ushort4 hi = {f2b(b.x), f2b(b.y), f2b(b.z), f2b(b.w)};
  *(ushort4*)(dst + (size_t)row * 1024 + c) = lo;
  *(ushort4*)(dst + (size_t)row * 1024 + c + 4) = hi;
}

// ---------------------------------------------------------------------------
// 128x128 GEMM tile, 256 threads: C = epilogue(A[M,K] @ B[N,K]^T), bf16 in.
// Device function; callers supply 32KB LDS and tile origin.
// ---------------------------------------------------------------------------
template<bool OUTF32, bool ACT, bool BIAS, bool RES, bool DUAL>
DEV void gemm_tile(char* sm,
    const u16* __restrict__ A, int lda, const u16* __restrict__ B, int ldb,
    void* Cp, int ldc, const float* __restrict__ bias,
    const float* res, int ldr, u16* C16, float alpha, int K, int m0, int n0)
{
  char* As = sm;
  char* Bs = sm + 16384;
  const int tid = threadIdx.x;
  const int lane = tid & 63, w = tid >> 6;
  const int wr = (w >> 1) * 64, wc = (w & 1) * 64;
  const int r_lo = lane & 15, kq = lane >> 4;

  __syncthreads();                       // protect LDS reuse across tiles

  f32x4 acc[4][4];
  #pragma unroll
  for (int i = 0; i < 4; ++i)
    #pragma unroll
    for (int j = 0; j < 4; ++j) acc[i][j] = (f32x4){0.f, 0.f, 0.f, 0.f};

  for (int kt = 0; kt < K; kt += 64) {
    if (kt) __syncthreads();
    #pragma unroll
    for (int i = 0; i < 4; ++i) {
      int f = i * 4096 + tid * 16;
      int row = f >> 7, colb = f & 127;
      int scol = colb ^ ((row & 7) << 4);
      load_lds16((const char*)(A + (size_t)(m0 + row) * lda + kt) + scol,
                 As + i * 4096 + w * 1024);
    }
    #pragma unroll
    for (int i = 0; i < 4; ++i) {
      int f = i * 4096 + tid * 16;
      int row = f >> 7, colb = f & 127;
      int scol = colb ^ ((row & 7) << 4);
      load_lds16((const char*)(B + (size_t)(n0 + row) * ldb + kt) + scol,
                 Bs + i * 4096 + w * 1024);
    }
    __syncthreads();
    #pragma unroll
    for (int ks = 0; ks < 2; ++ks) {
      s16x8 af[4], bfr[4];
      const int kb = ks * 64 + kq * 16;
      #pragma unroll
      for (int mi = 0; mi < 4; ++mi) {
        int row = wr + mi * 16 + r_lo;
        af[mi] = *(const s16x8*)(As + row * 128 + (kb ^ ((row & 7) << 4)));
      }
      #pragma unroll
      for (int ni = 0; ni < 4; ++ni) {
        int row = wc + ni * 16 + r_lo;
        bfr[ni] = *(const s16x8*)(Bs + row * 128 + (kb ^ ((row & 7) << 4)));
      }
      #pragma unroll
      for (int mi = 0; mi < 4; ++mi)
        #pragma unroll
        for (int ni = 0; ni < 4; ++ni)
          acc[mi][ni] = __builtin_amdgcn_mfma_f32_16x16x32_bf16(af[mi], bfr[ni], acc[mi][ni], 0, 0, 0);
    }
  }
  #pragma unroll
  for (int mi = 0; mi < 4; ++mi)
    #pragma unroll
    for (int ni = 0; ni < 4; ++ni)
      #pragma unroll
      for (int j = 0; j < 4; ++j) {
        int r = m0 + wr + mi * 16 + kq * 4 + j;
        int c = n0 + wc + ni * 16 + r_lo;
        float v = acc[mi][ni][j] * alpha;
        if (BIAS) v += bias[c];
        if (RES)  v += res[(size_t)r * ldr + c];
        if (ACT)  v = leaky(v);
        if (OUTF32) ((float*)Cp)[(size_t)r * ldc + c] = v;
        else        ((u16*)Cp)[(size_t)r * ldc + c] = f2b(v);
        if (DUAL)   C16[(size_t)r * ldc + c] = f2b(v);
      }
}

template<bool OUTF32, bool ACT, bool BIAS, bool RES, bool DUAL>
__global__ __launch_bounds__(256) void k_gemm_bt(
    const u16* __restrict__ A, int lda, const u16* __restrict__ B, int ldb,
    void* Cp, int ldc, const float* __restrict__ bias,
    const float* res, int ldr, u16* C16, float alpha, int K)
{
  __shared__ __align__(16) char sm[32768];
  gemm_tile<OUTF32, ACT, BIAS, RES, DUAL>(sm, A, lda, B, ldb, Cp, ldc, bias,
      res, ldr, C16, alpha, K, blockIdx.y * 128, blockIdx.x * 128);
}

// Batched RF3: grid (8,64); half = y>>5. C[half] = A[half] @ W3^T + rel_b.
__global__ __launch_bounds__(256) void k_rf3(
    const u16* __restrict__ G, const u16* __restrict__ relU,
    const u16* __restrict__ W3s, const float* __restrict__ rel_b,
    float* __restrict__ out_urel)
{
  __shared__ __align__(16) char sm[32768];
  int half = blockIdx.y >> 5;
  gemm_tile<true, false, true, false, false>(sm,
      half ? relU : G, Hn, W3s, Hn,
      out_urel + (size_t)half * 4096 * Hn, Hn, rel_b, nullptr, 0, nullptr,
      1.f, Hn, (blockIdx.y & 31) * 128, blockIdx.x * 128);
}

// ---------------------------------------------------------------------------
// Fused relation GEMM (both halves in one launch, grid (8,64)):
// C[half][4096x1024] += [upd16[sub] | upd16[obj]] @ [W1 | W2]^T  (K=2048).
// ---------------------------------------------------------------------------
__global__ __launch_bounds__(256) void k_gemm_rel(
    const u16* __restrict__ upd16, const int* __restrict__ rcm,
    const u16* __restrict__ W1, const u16* __restrict__ W2,
    float* __restrict__ out_urel)
{
  __shared__ __align__(16) char sm[32768];
  __shared__ int ridx[2][128];
  char* As = sm;
  char* Bs = sm + 16384;
  const int tid = threadIdx.x;
  const int lane = tid & 63, w = tid >> 6;
  const int hh = blockIdx.y >> 5;
  const int m0 = (blockIdx.y & 31) * 128, n0 = blockIdx.x * 128;
  const int wr = (w >> 1) * 64, wc = (w & 1) * 64;
  const int r_lo = lane & 15, kq = lane >> 4;
  const int* sub = rcm + hh * 4096;
  const int* obj = rcm + Rn + hh * 4096;
  float* C = out_urel + (size_t)hh * 4096 * Hn;

  if (tid < 128) ridx[0][tid] = sub[m0 + tid];
  else ridx[1][tid - 128] = obj[m0 + tid - 128];
  __syncthreads();

  f32x4 acc[4][4];
  #pragma unroll
  for (int i = 0; i < 4; ++i)
    #pragma unroll
    for (int j = 0; j < 4; ++j) acc[i][j] = (f32x4){0.f, 0.f, 0.f, 0.f};

  for (int kt = 0; kt < 2048; kt += 64) {
    const int half = kt >> 10;
    const int kk = kt & 1023;
    const u16* Wm = half ? W2 : W1;
    __syncthreads();
    #pragma unroll
    for (int i = 0; i < 4; ++i) {        // stage A (gathered rows)
      int f = i * 4096 + tid * 16;
      int row = f >> 7, colb = f & 127;
      int scol = colb ^ ((row & 7) << 4);
      load_lds16((const char*)(upd16 + (size_t)ridx[half][row] * 1024 + kk) + scol,
                 As + i * 4096 + w * 1024);
    }
    #pragma unroll
    for (int i = 0; i < 4; ++i) {        // stage B
      int f = i * 4096 + tid * 16;
      int row = f >> 7, colb = f & 127;
      int scol = colb ^ ((row & 7) << 4);
      load_lds16((const char*)(Wm + (size_t)(n0 + row) * 1024 + kk) + scol,
                 Bs + i * 4096 + w * 1024);
    }
    __syncthreads();
    #pragma unroll
    for (int ks = 0; ks < 2; ++ks) {
      s16x8 af[4], bfr[4];
      const int kb = ks * 64 + kq * 16;
      #pragma unroll
      for (int mi = 0; mi < 4; ++mi) {
        int row = wr + mi * 16 + r_lo;
        af[mi] = *(const s16x8*)(As + row * 128 + (kb ^ ((row & 7) << 4)));
      }
      #pragma unroll
      for (int ni = 0; ni < 4; ++ni) {
        int row = wc + ni * 16 + r_lo;
        bfr[ni] = *(const s16x8*)(Bs + row * 128 + (kb ^ ((row & 7) << 4)));
      }
      #pragma unroll
      for (int mi = 0; mi < 4; ++mi)
        #pragma unroll
        for (int ni = 0; ni < 4; ++ni)
          acc[mi][ni] = __builtin_amdgcn_mfma_f32_16x16x32_bf16(af[mi], bfr[ni], acc[mi][ni], 0, 0, 0);
    }
  }
  #pragma unroll
  for (int mi = 0; mi < 4; ++mi)
    #pragma unroll
    for (int ni = 0; ni < 4; ++ni)
      #pragma unroll
      for (int j = 0; j < 4; ++j) {
        int r = m0 + wr + mi * 16 + kq * 4 + j;
        int c = n0 + wc + ni * 16 + r_lo;
        C[(size_t)r * Hn + c] = acc[mi][ni][j] + C[(size_t)r * Hn + c];
      }
}

// ---------------------------------------------------------------------------
// MEGA: blocks 0..31 = GRU scan (MFMA matvec + packed u64 exchange, gated on
// gi completion). Blocks 32..255 = workers: Ph0 wf/wih cvt; bar; Ph1 gi GEMM
// tiles + cnt histogram; bar (releases GRU); scan (worker 0) + bulk cvts.
// ---------------------------------------------------------------------------
struct CvtTask { const float* src; u16* dst; int sld; int units; };
struct MKArgs {
  const float *w_hh_f, *w_hh_b, *b_hh_f, *b_hh_b;
  const float *word_feat, *w_ih_f, *w_ih_b, *b_ih_f, *b_ih_b;
  const int* rcm;
  float *gi_f, *gi_b;
  u16 *wf16, *wih16f, *wih16b;
  u64* X; int* cntX; int* pc; int* cnt2; int* offs; int* cursor;
  float* ctx;
  CvtTask t[11]; int nt;
};

__global__ __launch_bounds__(256) void k_mega(MKArgs a)
{
  __shared__ __align__(16) u16 wlds[96 * 512];   // GRU weights / worker GEMM LDS
  __shared__ float bh[96];
  __shared__ float partg[4][96];
  __shared__ __align__(16) u16 hb[512];          // h as f16 bits

  const int bid = blockIdx.x;
  const int tid = threadIdx.x;
  const int lane = tid & 63, wv = tid >> 6;
  const int NW = (int)gridDim.x - 32;

  if (bid >= 32) {
    // =================== WORKER PATH ===================
    const int bc = bid - 32, nb = NW;
    int bar = 0;
    auto wbarrier = [&]() {
      __syncthreads();
      if (tid == 0) {
        __hip_atomic_fetch_add(&a.pc[bar], 1, __ATOMIC_ACQ_REL, __HIP_MEMORY_SCOPE_AGENT);
        while (__hip_atomic_load(&a.pc[bar], __ATOMIC_ACQUIRE, __HIP_MEMORY_SCOPE_AGENT) < NW)
          __builtin_amdgcn_s_sleep(4);
      }
      __syncthreads();
      ++bar;
    };
    auto cvt_task = [&](const float* src, int sld, u16* dst, int units) {
      for (int u = bc * 256 + tid; u < units; u += nb * 256) {
        int row = u >> 7, c = (u & 127) * 8;
        const float* s = src + (size_t)row * sld + c;
        float4 va = *(const float4*)s;
        float4 vb = *(const float4*)(s + 4);
        ushort4 lo = {f2b(va.x), f2b(va.y), f2b(va.z), f2b(va.w)};
        ushort4 hi = {f2b(vb.x), f2b(vb.y), f2b(vb.z), f2b(vb.w)};
        *(ushort4*)(dst + (size_t)row * 1024 + c) = lo;
        *(ushort4*)(dst + (size_t)row * 1024 + c + 4) = hi;
      }
    };

    // Ph0: word/w_ih conversions
    cvt_task(a.word_feat, Hn, a.wf16, Wn * 128);
    cvt_task(a.w_ih_f, Hn, a.wih16f, 1536 * 128);
    cvt_task(a.w_ih_b, Hn, a.wih16b, 1536 * 128);
    wbarrier();                                   // bar0
    // Ph1: gi GEMM tiles (24) + cnt histogram
    for (int u = bc; u < 24; u += nb) {
      const u16* Bm = u < 12 ? a.wih16f : a.wih16b;
      float* Cm = u < 12 ? a.gi_f : a.gi_b;
      const float* bm = u < 12 ? a.b_ih_f : a.b_ih_b;
      gemm_tile<true, false, true, false, false>((char*)wlds, a.wf16, Hn, Bm, Hn,
          Cm, 1536, bm, nullptr, 0, nullptr, 1.f, Hn, 0, (u % 12) * 128);
    }
    for (int u = bc * 256 + tid; u < 2 * Rn; u += nb * 256) {
      if (u < Rn && a.rcm[u] == a.rcm[Rn + u]) continue;
      atomicAdd(a.cnt2 + a.rcm[u], 1);
    }
    wbarrier();                                   // bar1 (releases GRU)
    // scan (worker 0) + bulk conversions
    if (bc == 0) {
      int* part = (int*)wlds;
      int* pscan = part + 256;
      int loc[16]; int s = 0;
      #pragma unroll
      for (int i = 0; i < 16; ++i) { loc[i] = a.cnt2[tid * 16 + i]; s += loc[i]; }
      part[tid] = s; __syncthreads();
      if (tid == 0) { int acc = 0; for (int i = 0; i < 256; ++i) { pscan[i] = acc; acc += part[i]; } }
      __syncthreads();
      int base = pscan[tid];
      #pragma unroll
      for (int i = 0; i < 16; ++i) {
        a.offs[tid * 16 + i] = base; a.cursor[tid * 16 + i] = base; base += loc[i];
      }
      if (tid == 255) a.offs[Pn] = base;
    }
    for (int k = 0; k < a.nt; ++k)
      cvt_task(a.t[k].src, a.t[k].sld, a.t[k].dst, a.t[k].units);
    return;
  }

  // =================== GRU PATH (blocks 0..31) ===================
  const int dir = bid >> 4;
  const int b   = bid & 15;
  const float* w_hh = dir ? a.w_hh_b : a.w_hh_f;
  const float* b_hhp = dir ? a.b_hh_b : a.b_hh_f;
  const float* gi = dir ? a.gi_b : a.gi_f;
  u64* Xd = a.X + (size_t)dir * 128 * 128;
  int* cntD = a.cntX + dir * 128;

  // weights f32 -> f16 LDS, row-major 1KB rows, byte ^ ((row&7)<<4) swizzle
  for (int idx = tid; idx < 96 * 128; idx += 256) {
    int gl = idx >> 7;
    int kc = (idx & 127) << 2;
    int g  = 32 * b + (gl & 31) + ((gl >> 5) << 9);
    float4 wv4 = *(const float4*)(w_hh + (size_t)g * 512 + kc);
    u16 d4[4] = {f2h(wv4.x), f2h(wv4.y), f2h(wv4.z), f2h(wv4.w)};
    int byte = (kc * 2) ^ ((gl & 7) << 4);
    *(uint2*)((char*)wlds + gl * 1024 + byte) = *(uint2*)d4;
  }
  if (tid < 96) {
    int g = 32 * b + (tid & 31) + ((tid >> 5) << 9);
    bh[tid] = b_hhp[g];
  }
  for (int i = tid; i < 256; i += 256) ((unsigned*)hb)[i] = 0u;
  // wait for gi (worker barrier index 1)
  if (tid == 0) {
    while (__hip_atomic_load(&a.pc[1], __ATOMIC_ACQUIRE, __HIP_MEMORY_SCOPE_AGENT) < NW)
      __builtin_amdgcn_s_sleep(16);
  }
  __syncthreads();

  float hprev = 0.f;
  const int jg = 32 * b + tid;          // tid<32 meaningful
  const int r_lo = lane & 15, kq = lane >> 4;
  const fp16x8 zf = {0, 0, 0, 0, 0, 0, 0, 0};

  for (int sidx = 0; sidx < 128; ++sidx) {
    const int t = dir ? (127 - sidx) : sidx;

    float gir = 0.f, giz = 0.f, gin = 0.f;
    if (tid < 32) {                     // prefetch under MFMA phase
      gir = gi[t * 1536 + jg];
      giz = gi[t * 1536 + 512 + jg];
      gin = gi[t * 1536 + 1024 + jg];
    }

    // MFMA matvec: wave wv covers K-tiles wv*4..wv*4+3, all 6 gate-tiles
    f32x4 acc6[6];
    #pragma unroll
    for (int gt = 0; gt < 6; ++gt) acc6[gt] = (f32x4){0.f, 0.f, 0.f, 0.f};
    #pragma unroll
    for (int k2 = 0; k2 < 4; ++k2) {
      int kt = (wv << 2) + k2;
      fp16x8 bf = (r_lo == 0) ? *(const fp16x8*)(hb + kt * 32 + kq * 8) : zf;
      #pragma unroll
      for (int gt = 0; gt < 6; ++gt) {
        int gl = gt * 16 + r_lo;
        int byte = (kt * 64 + kq * 16) ^ ((gl & 7) << 4);
        fp16x8 af = *(const fp16x8*)((const char*)wlds + gl * 1024 + byte);
        acc6[gt] = __builtin_amdgcn_mfma_f32_16x16x32_f16(af, bf, acc6[gt], 0, 0, 0);
      }
    }
    if (r_lo == 0) {                    // col-0 lanes: rows kq*4+j
      #pragma unroll
      for (int gt = 0; gt < 6; ++gt)
        #pragma unroll
        for (int j = 0; j < 4; ++j)
          partg[wv][gt * 16 + kq * 4 + j] = acc6[gt][j];
    }
    __syncthreads();

    if (wv == 0) {
      float h2v = 0.f;
      if (lane < 32) {
        int j = lane;
        float ghr = partg[0][j] + partg[1][j] + partg[2][j] + partg[3][j] + bh[j];
        float ghz = partg[0][j + 32] + partg[1][j + 32] + partg[2][j + 32] + partg[3][j + 32] + bh[j + 32];
        float ghn = partg[0][j + 64] + partg[1][j + 64] + partg[2][j + 64] + partg[3][j + 64] + bh[j + 64];
        float rr = 1.f / (1.f + __expf(-(gir + ghr)));
        float zz = 1.f / (1.f + __expf(-(giz + ghz)));
        float nn = tanhf(gin + rr * ghn);
        h2v = (1.f - zz) * nn + zz * hprev;
        hprev = h2v;
        if (sidx == 0)   a.ctx[(dir ? 1536 : 0)    + jg] = h2v;
        if (sidx == 127) a.ctx[(dir ? 512  : 1024) + jg] = h2v;
      }
      if (sidx < 127) {
        int l4 = (lane & 7) * 4;        // pack 4 h into one u64
        float p0 = __shfl(h2v, l4 + 0, 64);
        float p1 = __shfl(h2v, l4 + 1, 64);
        float p2 = __shfl(h2v, l4 + 2, 64);
        float p3 = __shfl(h2v, l4 + 3, 64);
        if (lane < 8) {
          u64 pk = (u64)f2h(p0) | ((u64)f2h(p1) << 16) |
                   ((u64)f2h(p2) << 32) | ((u64)f2h(p3) << 48);
          __hip_atomic_store(&Xd[(size_t)sidx * 128 + b * 8 + lane], pk,
                             __ATOMIC_RELAXED, __HIP_MEMORY_SCOPE_AGENT);
        }
        if (lane == 0)
          __hip_atomic_fetch_add(&cntD[sidx], 1, __ATOMIC_RELEASE,
                                 __HIP_MEMORY_SCOPE_AGENT);
        while (__hip_atomic_load(&cntD[sidx], __ATOMIC_ACQUIRE,
                                 __HIP_MEMORY_SCOPE_AGENT) < 16)
          __builtin_amdgcn_s_sleep(1);
        const u64* src = Xd + (size_t)sidx * 128;
        u64 w0 = __hip_atomic_load(&src[2 * lane],     __ATOMIC_RELAXED, __HIP_MEMORY_SCOPE_AGENT);
        u64 w1 = __hip_atomic_load(&src[2 * lane + 1], __ATOMIC_RELAXED, __HIP_MEMORY_SCOPE_AGENT);
        *(u64*)(hb + lane * 8)     = w0;
        *(u64*)(hb + lane * 8 + 4) = w1;
      }
    }
    __syncthreads();                    // hb ready for all waves
  }
}

// ---------------------------------------------------------------------------
// small kernels
// ---------------------------------------------------------------------------
__global__ __launch_bounds__(256) void k_softmax1(
    const float* __restrict__ scores, const int* __restrict__ conn, u16* __restrict__ attw)
{
  int p = blockIdx.x * 4 + (threadIdx.x >> 6);
  int lane = threadIdx.x & 63;
  float v0 = scores[(size_t)p * 128 + lane];
  float v1 = scores[(size_t)p * 128 + 64 + lane];
  int m0 = conn[(size_t)p * 128 + lane];
  int m1 = conn[(size_t)p * 128 + 64 + lane];
  float x0 = m0 > 0 ? v0 : -INFINITY;
  float x1 = m1 > 0 ? v1 : -INFINITY;
  float mx = wred_max(fmaxf(x0, x1));
  if (!(mx > -INFINITY)) mx = 0.f;
  float e0 = m0 > 0 ? __expf(v0 - mx) : 0.f;
  float e1 = m1 > 0 ? __expf(v1 - mx) : 0.f;
  float s = wred_sum(e0 + e1);
  float inv = 1.f / (s + 1e-6f);
  attw[(size_t)p * 128 + lane] = f2b(e0 * inv);
  attw[(size_t)p * 128 + 64 + lane] = f2b(e1 * inv);
}

__global__ __launch_bounds__(256) void k_transpose(const u16* __restrict__ in, u16* __restrict__ out)
{
  int idx = blockIdx.x * 256 + threadIdx.x;   // over 128*1024
  int r = idx >> 10, c = idx & 1023;
  out[c * 128 + r] = in[idx];
}

__global__ __launch_bounds__(256) void k_cvec(const float* __restrict__ att1W,
    const float* __restrict__ att1b, const float* __restrict__ ctx, float* __restrict__ cvec)
{
  int i = blockIdx.x * 4 + (threadIdx.x >> 6);
  int lane = threadIdx.x & 63;
  const float* wrow = att1W + (size_t)i * 4096 + 2048 + lane * 32;
  const float* cp = ctx + lane * 32;
  float acc = 0.f;
  #pragma unroll
  for (int k = 0; k < 32; ++k) acc += wrow[k] * cp[k];
  acc = wred_sum(acc);
  if (lane == 0) cvec[i] = acc + att1b[i];
}

__global__ __launch_bounds__(256) void k_edge_s(const int* __restrict__ rcm,
    const u16* __restrict__ U1, const u16* __restrict__ V1, const float* __restrict__ cvec,
    const float* __restrict__ att2w, const float* __restrict__ att2b,
    float* __restrict__ sval)
{
  int idx = blockIdx.x * 4 + (threadIdx.x >> 6);   // [0, 2*Rn)
  int lane = threadIdx.x & 63;
  int rL = idx < Rn ? idx : idx - Rn;
  int p = rcm[idx];
  const u16* u = U1 + (size_t)p * Hn + lane * 16;
  const u16* v = V1 + (size_t)rL * Hn + lane * 16;
  const float* aw = att2w + lane * 16;
  const float* cv = cvec + lane * 16;
  float acc = 0.f;
  #pragma unroll
  for (int i = 0; i < 16; ++i) {
    float x = b2f(u[i]) + b2f(v[i]) + cv[i];
    acc += aw[i] * leaky(x);
  }
  acc = wred_sum(acc);
  if (lane == 0) sval[idx] = acc + att2b[0];
}

__global__ __launch_bounds__(256) void k_fill(const int* __restrict__ rcm,
    const float* __restrict__ sval, int* __restrict__ cursor,
    int* __restrict__ er, float* __restrict__ es)
{
  int e = blockIdx.x * 256 + threadIdx.x;
  if (e < Rn && rcm[e] == rcm[Rn + e]) return;
  int slot = atomicAdd(cursor + rcm[e], 1);
  er[slot] = e & (Rn - 1);
  es[slot] = sval[e];
}

__global__ __launch_bounds__(256) void k_att_apply(const int* __restrict__ offs,
    const int* __restrict__ er, const float* __restrict__ es,
    const float* __restrict__ urel, u16* __restrict__ pacc)
{
  int p = blockIdx.x;
  int tid = threadIdx.x;
  int beg = offs[p], end = offs[p + 1];
  float mx = -INFINITY;
  for (int i = beg; i < end; ++i) mx = fmaxf(mx, es[i]);
  float den = 1e-6f;
  for (int i = beg; i < end; ++i) den += __expf(es[i] - mx);
  float inv = 1.f / den;
  float a0 = 0.f, a1 = 0.f, a2 = 0.f, a3 = 0.f;
  int c0 = tid * 4;
  for (int i = beg; i < end; ++i) {
    float wgt = __expf(es[i] - mx) * inv;
    float4 q = *(const float4*)(urel + (size_t)er[i] * Hn + c0);
    a0 += wgt * q.x; a1 += wgt * q.y; a2 += wgt * q.z; a3 += wgt * q.w;
  }
  ushort4 ov; ov.x = f2b(a0); ov.y = f2b(a1); ov.z = f2b(a2); ov.w = f2b(a3);
  *(ushort4*)(pacc + (size_t)p * Hn + c0) = ov;
}

// ---------------------------------------------------------------------------
extern "C" void kernel_launch(void* const* d_in, const int* in_sizes, int n_in,
                              void* d_out, int out_size, void* d_ws, size_t ws_size,
                              hipStream_t stream)
{
  const float* word_feat   = (const float*)d_in[0];
  const float* phrase_feat = (const float*)d_in[1];
  const float* rel_feat    = (const float*)d_in[2];
  const float* w_ih_f = (const float*)d_in[3];
  const float* w_hh_f = (const float*)d_in[4];
  const float* b_ih_f = (const float*)d_in[5];
  const float* b_hh_f = (const float*)d_in[6];
  const float* w_ih_b = (const float*)d_in[7];
  const float* w_hh_b = (const float*)d_in[8];
  const float* b_ih_b = (const float*)d_in[9];
  const float* b_hh_b = (const float*)d_in[10];
  const float* w2p_w_W = (const float*)d_in[11];
  const float* w2p_w_b = (const float*)d_in[12];
  const float* w2p_p_W = (const float*)d_in[13];
  const float* w2p_p_b = (const float*)d_in[14];
  const float* w2p_t_W = (const float*)d_in[15];
  const float* w2p_t_b = (const float*)d_in[16];
  const float* rel_W   = (const float*)d_in[17];
  const float* rel_b   = (const float*)d_in[18];
  const float* att1_W  = (const float*)d_in[19];
  const float* att1_b  = (const float*)d_in[20];
  const float* att2_W  = (const float*)d_in[21];
  const float* att2_b  = (const float*)d_in[22];
  const float* r2p_t_W = (const float*)d_in[23];
  const float* r2p_t_b = (const float*)d_in[24];
  const int* rcm  = (const int*)d_in[25];
  const int* conn = (const int*)d_in[26];

  float* out_word = (float*)d_out;
  float* out_phr  = out_word + (size_t)Wn * Hn;   // 4096x1024 f32
  float* out_urel = out_phr + (size_t)Pn * Hn;    // 8192x1024 f32

  // ---- workspace (~44.5 MB, proven layout) ----
  char* ws = (char*)d_ws;
  size_t off = 0;
  auto alloc = [&](size_t bytes) -> char* {
    char* pptr = ws + off; off += (bytes + 255) & ~(size_t)255; return pptr;
  };
  int*   cnt2   = (int*)alloc(Pn * 4);                    // } zeroed together
  int*   pc     = (int*)alloc(64 * 4);                    // }
  int*   cntX   = (int*)alloc(256 * 4);                   // }
  u64*   X      = (u64*)alloc(2 * 128 * 128 * 8);         // }
  size_t zlen   = (size_t)((char*)(X + 2 * 128 * 128) - (char*)cnt2);
  float* ctx    = (float*)alloc(2048 * 4);
  float* cvec   = (float*)alloc(1024 * 4);
  int*   cursor = (int*)alloc(Pn * 4);
  int*   offs   = (int*)alloc((Pn + 1) * 4);
  int*   er     = (int*)alloc(2 * Rn * 4);
  float* es     = (float*)alloc(2 * Rn * 4);
  float* sval   = (float*)alloc(2 * Rn * 4);
  float* gi_f   = (float*)alloc(128 * 1536 * 4);
  float* gi_b   = (float*)alloc(128 * 1536 * 4);
  u16*   wf16   = (u16*)alloc((size_t)Wn * Hn * 2);
  u16*   wl     = (u16*)alloc((size_t)Wn * Hn * 2);
  u16*   upd16  = (u16*)alloc((size_t)Pn * Hn * 2);       // later: pacc
  char*  RA     = alloc(16777216);                        // W1s/W2s/W3s/G -> V1f
  u16*   W1s    = (u16*)RA;
  u16*   W2s    = (u16*)(RA + 2097152);
  u16*   W3s    = (u16*)(RA + 4194304);
  u16*   G      = (u16*)(RA + 6291456);                   // 8.39MB (rel lower)
  u16*   V1f    = (u16*)RA;                               // 16.78MB (late)
  u16*   A1p16  = (u16*)alloc(2097152);
  u16*   A1r16  = (u16*)alloc(2097152);
  u16*   U1     = (u16*)alloc((size_t)Pn * Hn * 2);       // relU16 early, U1 late
  u16*   relU16 = U1;                                     // rel upper bf16 (dies at RF3)
  char*  CBr    = alloc(4194304);                         // urel cvt chunk
  u16*   CB     = (u16*)CBr;
  u16*   r2pW16 = (u16*)CBr;                              // after CB dead
  u16*   pacc   = upd16;                                  // after U1 GEMM done

  // ---- d_out regions as early scratch ----
  char* phrB = (char*)out_phr;
  u16*   wih16f = (u16*)phrB;                           // 3.15MB
  u16*   wih16b = (u16*)(phrB + 3145728);               // 3.15MB
  float* scores = (float*)(phrB + 6291456);             // 2.10MB
  char* urlB = (char*)out_urel;
  u16*   pf16   = (u16*)urlB;                           // 8.39MB
  u16*   w2pw16 = (u16*)(urlB + 8388608);
  u16*   w2pp16 = (u16*)(urlB + 10485760);
  u16*   w2pt16 = (u16*)(urlB + 12582912);
  u16*   pl     = (u16*)(urlB + 14680064);              // 8.39MB
  u16*   aw     = (u16*)(urlB + 23068672);              // 8.39MB
  u16*   attw   = (u16*)(urlB + 31457280);              // 1.05MB
  u16*   wfT    = (u16*)(urlB + 32505856);              // 0.26MB

  (void)hipMemsetAsync(cnt2, 0, zlen, stream);

  dim3 blk(256);

  // mega: GRU || {wf/wih cvt -> gi GEMMs + cnt -> scan + bulk cvts}
  MKArgs A;
  A.w_hh_f = w_hh_f; A.w_hh_b = w_hh_b; A.b_hh_f = b_hh_f; A.b_hh_b = b_hh_b;
  A.word_feat = word_feat; A.w_ih_f = w_ih_f; A.w_ih_b = w_ih_b;
  A.b_ih_f = b_ih_f; A.b_ih_b = b_ih_b; A.rcm = rcm;
  A.gi_f = gi_f; A.gi_b = gi_b;
  A.wf16 = wf16; A.wih16f = wih16f; A.wih16b = wih16b;
  A.X = X; A.cntX = cntX; A.pc = pc; A.cnt2 = cnt2;
  A.offs = offs; A.cursor = cursor; A.ctx = ctx;
  A.t[0]  = {phrase_feat,    pf16,   Hn,     Pn * 128};
  A.t[1]  = {w2p_w_W,        w2pw16, Hn,     1024 * 128};
  A.t[2]  = {w2p_p_W,        w2pp16, Hn,     1024 * 128};
  A.t[3]  = {w2p_t_W,        w2pt16, Hn,     1024 * 128};
  A.t[4]  = {rel_W,          W1s,    3 * Hn, 1024 * 128};
  A.t[5]  = {rel_W + Hn,     W2s,    3 * Hn, 1024 * 128};
  A.t[6]  = {rel_W + 2 * Hn, W3s,    3 * Hn, 1024 * 128};
  A.t[7]  = {att1_W,         A1p16,  4 * Hn, 1024 * 128};
  A.t[8]  = {att1_W + Hn,    A1r16,  4 * Hn, 1024 * 128};
  A.t[9]  = {rel_feat,       G,      Hn,     4096 * 128};            // rel lower
  A.t[10] = {rel_feat + (size_t)4096 * Hn, relU16, Hn, 4096 * 128};  // rel upper
  A.nt = 11;
  k_mega<<<256, blk, 0, stream>>>(A);
  k_cvec<<<256, blk, 0, stream>>>(att1_W, att1_b, ctx, cvec);

  // word->phrase attention; upd (f32 in out_phr + bf16 copy)
  k_gemm_bt<false, true, true, false, false><<<dim3(8, 1), blk, 0, stream>>>(
      wf16, Hn, w2pw16, Hn, wl, Hn, w2p_w_b, nullptr, 0, nullptr, 1.f, Hn);
  k_gemm_bt<false, true, true, false, false><<<dim3(8, 32), blk, 0, stream>>>(
      pf16, Hn, w2pp16, Hn, pl, Hn, w2p_p_b, nullptr, 0, nullptr, 1.f, Hn);
  k_gemm_bt<true, false, false, false, false><<<dim3(1, 32), blk, 0, stream>>>(
      pl, Hn, wl, Hn, scores, Wn, nullptr, nullptr, 0, nullptr, 0.03125f, Hn);
  k_softmax1<<<Pn / 4, blk, 0, stream>>>(scores, conn, attw);
  k_transpose<<<(Wn * Hn) / 256, blk, 0, stream>>>(wf16, wfT);
  k_gemm_bt<false, false, false, false, false><<<dim3(8, 32), blk, 0, stream>>>(
      attw, Wn, wfT, Wn, aw, Hn, nullptr, nullptr, 0, nullptr, 1.f, Wn);
  k_gemm_bt<true, false, true, true, true><<<dim3(8, 32), blk, 0, stream>>>(
      aw, Hn, w2pt16, Hn, out_phr, Hn, w2p_t_b, phrase_feat, Hn, upd16, 1.f, Hn);

  // urel: batched RF3 (both halves), then batched dual-gather accumulate
  k_rf3<<<dim3(8, 64), blk, 0, stream>>>(G, relU16, W3s, rel_b, out_urel);
  k_gemm_rel<<<dim3(8, 64), blk, 0, stream>>>(upd16, rcm, W1s, W2s, out_urel);

  // U1 then V1 (4 chunks of 2048 rows into V1f over RA)
  k_gemm_bt<false, false, false, false, false><<<dim3(8, 32), blk, 0, stream>>>(
      upd16, Hn, A1p16, Hn, U1, Hn, nullptr, nullptr, 0, nullptr, 1.f, Hn);
  for (int cb = 0; cb < Rn; cb += 2048) {
    k_cvt<<<1024, blk, 0, stream>>>(out_urel + (size_t)cb * Hn, Hn, CB);
    k_gemm_bt<false, false, false, false, false><<<dim3(8, 16), blk, 0, stream>>>(
        CB, Hn, A1r16, Hn, V1f + (size_t)cb * Hn, Hn, nullptr, nullptr, 0,
        nullptr, 1.f, Hn);
  }
  k_cvt<<<512, blk, 0, stream>>>(r2p_t_W, Hn, r2pW16);   // CB dead now

  // edge scores + CSR softmax + att@urel + final residual GEMM
  k_edge_s<<<(2 * Rn) / 4, blk, 0, stream>>>(rcm, U1, V1f, cvec, att2_W, att2_b, sval);
  k_fill<<<(2 * Rn) / 256, blk, 0, stream>>>(rcm, sval, cursor, er, es);
  k_att_apply<<<Pn, blk, 0, stream>>>(offs, er, es, out_urel, pacc);
  k_gemm_bt<true, false, true, true, false><<<dim3(8, 32), blk, 0, stream>>>(
      pacc, Hn, r2pW16, Hn, out_phr, Hn, r2p_t_b, out_phr, Hn, nullptr, 1.f, Hn);

  (void)hipMemcpyAsync(out_word, word_feat, (size_t)Wn * Hn * 4,
                       hipMemcpyDeviceToDevice, stream);
}

// Round 12
// 736.866 us; speedup vs baseline: 1.3063x; 1.0831x over previous
//
#include <hip/hip_runtime.h>

#define DEV __device__ __forceinline__

typedef short s16x8 __attribute__((ext_vector_type(8)));
typedef float f32x4 __attribute__((ext_vector_type(4)));
typedef __fp16 fp16x8 __attribute__((ext_vector_type(8)));
typedef unsigned short u16;
typedef unsigned long long u64;

constexpr int Wn = 128;    // words
constexpr int Pn = 4096;   // phrases
constexpr int Rn = 8192;   // relations
constexpr int Hn = 1024;   // hidden

DEV float b2f(u16 u) { union { unsigned i; float f; } x; x.i = (unsigned)u << 16; return x.f; }
DEV u16 f2b(float f) {
  union { float f; unsigned i; } x; x.f = f;
  unsigned r = x.i + 0x7FFF + ((x.i >> 16) & 1);   // RNE
  return (u16)(r >> 16);
}
DEV u16 f2h(float x) { __fp16 h = (__fp16)x; u16 r; __builtin_memcpy(&r, &h, 2); return r; }
DEV float leaky(float x) { return x >= 0.f ? x : 0.01f * x; }

DEV void load_lds16(const void* g, void* l) {
  __builtin_amdgcn_global_load_lds(
      (const __attribute__((address_space(1))) void*)g,
      (__attribute__((address_space(3))) void*)l, 16, 0, 0);
}

DEV float wred_sum(float v) {
  #pragma unroll
  for (int m = 1; m < 64; m <<= 1) v += __shfl_xor(v, m, 64);
  return v;
}
DEV float wred_max(float v) {
  #pragma unroll
  for (int m = 1; m < 64; m <<= 1) v = fmaxf(v, __shfl_xor(v, m, 64));
  return v;
}

// ---------------------------------------------------------------------------
// 128x128 GEMM tile, 256 threads: C = epilogue(A[M,K] @ B[N,K]^T), bf16 in.
// ---------------------------------------------------------------------------
template<bool OUTF32, bool ACT, bool BIAS, bool RES, bool DUAL>
DEV void gemm_tile(char* sm,
    const u16* __restrict__ A, int lda, const u16* __restrict__ B, int ldb,
    void* Cp, int ldc, const float* __restrict__ bias,
    const float* res, int ldr, u16* C16, float alpha, int K, int m0, int n0)
{
  char* As = sm;
  char* Bs = sm + 16384;
  const int tid = threadIdx.x;
  const int lane = tid & 63, w = tid >> 6;
  const int wr = (w >> 1) * 64, wc = (w & 1) * 64;
  const int r_lo = lane & 15, kq = lane >> 4;

  __syncthreads();                       // protect LDS reuse across tiles

  f32x4 acc[4][4];
  #pragma unroll
  for (int i = 0; i < 4; ++i)
    #pragma unroll
    for (int j = 0; j < 4; ++j) acc[i][j] = (f32x4){0.f, 0.f, 0.f, 0.f};

  for (int kt = 0; kt < K; kt += 64) {
    if (kt) __syncthreads();
    #pragma unroll
    for (int i = 0; i < 4; ++i) {
      int f = i * 4096 + tid * 16;
      int row = f >> 7, colb = f & 127;
      int scol = colb ^ ((row & 7) << 4);
      load_lds16((const char*)(A + (size_t)(m0 + row) * lda + kt) + scol,
                 As + i * 4096 + w * 1024);
    }
    #pragma unroll
    for (int i = 0; i < 4; ++i) {
      int f = i * 4096 + tid * 16;
      int row = f >> 7, colb = f & 127;
      int scol = colb ^ ((row & 7) << 4);
      load_lds16((const char*)(B + (size_t)(n0 + row) * ldb + kt) + scol,
                 Bs + i * 4096 + w * 1024);
    }
    __syncthreads();
    #pragma unroll
    for (int ks = 0; ks < 2; ++ks) {
      s16x8 af[4], bfr[4];
      const int kb = ks * 64 + kq * 16;
      #pragma unroll
      for (int mi = 0; mi < 4; ++mi) {
        int row = wr + mi * 16 + r_lo;
        af[mi] = *(const s16x8*)(As + row * 128 + (kb ^ ((row & 7) << 4)));
      }
      #pragma unroll
      for (int ni = 0; ni < 4; ++ni) {
        int row = wc + ni * 16 + r_lo;
        bfr[ni] = *(const s16x8*)(Bs + row * 128 + (kb ^ ((row & 7) << 4)));
      }
      #pragma unroll
      for (int mi = 0; mi < 4; ++mi)
        #pragma unroll
        for (int ni = 0; ni < 4; ++ni)
          acc[mi][ni] = __builtin_amdgcn_mfma_f32_16x16x32_bf16(af[mi], bfr[ni], acc[mi][ni], 0, 0, 0);
    }
  }
  #pragma unroll
  for (int mi = 0; mi < 4; ++mi)
    #pragma unroll
    for (int ni = 0; ni < 4; ++ni)
      #pragma unroll
      for (int j = 0; j < 4; ++j) {
        int r = m0 + wr + mi * 16 + kq * 4 + j;
        int c = n0 + wc + ni * 16 + r_lo;
        float v = acc[mi][ni][j] * alpha;
        if (BIAS) v += bias[c];
        if (RES)  v += res[(size_t)r * ldr + c];
        if (ACT)  v = leaky(v);
        if (OUTF32) ((float*)Cp)[(size_t)r * ldc + c] = v;
        else        ((u16*)Cp)[(size_t)r * ldc + c] = f2b(v);
        if (DUAL)   C16[(size_t)r * ldc + c] = f2b(v);
      }
}

template<bool OUTF32, bool ACT, bool BIAS, bool RES, bool DUAL>
__global__ __launch_bounds__(256) void k_gemm_bt(
    const u16* __restrict__ A, int lda, const u16* __restrict__ B, int ldb,
    void* Cp, int ldc, const float* __restrict__ bias,
    const float* res, int ldr, u16* C16, float alpha, int K)
{
  __shared__ __align__(16) char sm[32768];
  gemm_tile<OUTF32, ACT, BIAS, RES, DUAL>(sm, A, lda, B, ldb, Cp, ldc, bias,
      res, ldr, C16, alpha, K, blockIdx.y * 128, blockIdx.x * 128);
}

// GEMM with f32 A (on-the-fly bf16 convert via swizzled ds_write), bf16 out.
__global__ __launch_bounds__(256) void k_gemm_af32(
    const float* __restrict__ A, int lda, const u16* __restrict__ B, int ldb,
    u16* __restrict__ C, int ldc, int K)
{
  __shared__ __align__(16) char sm[32768];
  char* As = sm;
  char* Bs = sm + 16384;
  const int tid = threadIdx.x;
  const int lane = tid & 63, w = tid >> 6;
  const int m0 = blockIdx.y * 128, n0 = blockIdx.x * 128;
  const int wr = (w >> 1) * 64, wc = (w & 1) * 64;
  const int r_lo = lane & 15, kq = lane >> 4;

  f32x4 acc[4][4];
  #pragma unroll
  for (int i = 0; i < 4; ++i)
    #pragma unroll
    for (int j = 0; j < 4; ++j) acc[i][j] = (f32x4){0.f, 0.f, 0.f, 0.f};

  for (int kt = 0; kt < K; kt += 64) {
    if (kt) __syncthreads();
    #pragma unroll
    for (int i = 0; i < 4; ++i) {        // stage A: f32 -> bf16, swizzled
      int e = i * 2048 + tid * 8;        // element index
      int row = e >> 6, col = e & 63;
      const float* s = A + (size_t)(m0 + row) * lda + kt + col;
      float4 a4 = *(const float4*)s;
      float4 b4 = *(const float4*)(s + 4);
      u16 d8[8] = {f2b(a4.x), f2b(a4.y), f2b(a4.z), f2b(a4.w),
                   f2b(b4.x), f2b(b4.y), f2b(b4.z), f2b(b4.w)};
      int byte = (col * 2) ^ ((row & 7) << 4);
      *(uint4*)(As + row * 128 + byte) = *(uint4*)d8;
    }
    #pragma unroll
    for (int i = 0; i < 4; ++i) {        // stage B
      int f = i * 4096 + tid * 16;
      int row = f >> 7, colb = f & 127;
      int scol = colb ^ ((row & 7) << 4);
      load_lds16((const char*)(B + (size_t)(n0 + row) * ldb + kt) + scol,
                 Bs + i * 4096 + w * 1024);
    }
    __syncthreads();
    #pragma unroll
    for (int ks = 0; ks < 2; ++ks) {
      s16x8 af[4], bfr[4];
      const int kb = ks * 64 + kq * 16;
      #pragma unroll
      for (int mi = 0; mi < 4; ++mi) {
        int row = wr + mi * 16 + r_lo;
        af[mi] = *(const s16x8*)(As + row * 128 + (kb ^ ((row & 7) << 4)));
      }
      #pragma unroll
      for (int ni = 0; ni < 4; ++ni) {
        int row = wc + ni * 16 + r_lo;
        bfr[ni] = *(const s16x8*)(Bs + row * 128 + (kb ^ ((row & 7) << 4)));
      }
      #pragma unroll
      for (int mi = 0; mi < 4; ++mi)
        #pragma unroll
        for (int ni = 0; ni < 4; ++ni)
          acc[mi][ni] = __builtin_amdgcn_mfma_f32_16x16x32_bf16(af[mi], bfr[ni], acc[mi][ni], 0, 0, 0);
    }
  }
  #pragma unroll
  for (int mi = 0; mi < 4; ++mi)
    #pragma unroll
    for (int ni = 0; ni < 4; ++ni)
      #pragma unroll
      for (int j = 0; j < 4; ++j) {
        int r = m0 + wr + mi * 16 + kq * 4 + j;
        int c = n0 + wc + ni * 16 + r_lo;
        C[(size_t)r * ldc + c] = f2b(acc[mi][ni][j]);
      }
}

// Batched RF3: grid (8,64); half = y>>5. C[half] = A[half] @ W3^T + rel_b.
__global__ __launch_bounds__(256) void k_rf3(
    const u16* __restrict__ G, const u16* __restrict__ relU,
    const u16* __restrict__ W3s, const float* __restrict__ rel_b,
    float* __restrict__ out_urel)
{
  __shared__ __align__(16) char sm[32768];
  int half = blockIdx.y >> 5;
  gemm_tile<true, false, true, false, false>(sm,
      half ? relU : G, Hn, W3s, Hn,
      out_urel + (size_t)half * 4096 * Hn, Hn, rel_b, nullptr, 0, nullptr,
      1.f, Hn, (blockIdx.y & 31) * 128, blockIdx.x * 128);
}

// ---------------------------------------------------------------------------
// Fused relation GEMM (both halves, grid (8,64)):
// C[half][4096x1024] += [upd16[sub] | upd16[obj]] @ [W1 | W2]^T  (K=2048).
// ---------------------------------------------------------------------------
__global__ __launch_bounds__(256) void k_gemm_rel(
    const u16* __restrict__ upd16, const int* __restrict__ rcm,
    const u16* __restrict__ W1, const u16* __restrict__ W2,
    float* __restrict__ out_urel)
{
  __shared__ __align__(16) char sm[32768];
  __shared__ int ridx[2][128];
  char* As = sm;
  char* Bs = sm + 16384;
  const int tid = threadIdx.x;
  const int lane = tid & 63, w = tid >> 6;
  const int hh = blockIdx.y >> 5;
  const int m0 = (blockIdx.y & 31) * 128, n0 = blockIdx.x * 128;
  const int wr = (w >> 1) * 64, wc = (w & 1) * 64;
  const int r_lo = lane & 15, kq = lane >> 4;
  const int* sub = rcm + hh * 4096;
  const int* obj = rcm + Rn + hh * 4096;
  float* C = out_urel + (size_t)hh * 4096 * Hn;

  if (tid < 128) ridx[0][tid] = sub[m0 + tid];
  else ridx[1][tid - 128] = obj[m0 + tid - 128];
  __syncthreads();

  f32x4 acc[4][4];
  #pragma unroll
  for (int i = 0; i < 4; ++i)
    #pragma unroll
    for (int j = 0; j < 4; ++j) acc[i][j] = (f32x4){0.f, 0.f, 0.f, 0.f};

  for (int kt = 0; kt < 2048; kt += 64) {
    const int half = kt >> 10;
    const int kk = kt & 1023;
    const u16* Wm = half ? W2 : W1;
    __syncthreads();
    #pragma unroll
    for (int i = 0; i < 4; ++i) {        // stage A (gathered rows)
      int f = i * 4096 + tid * 16;
      int row = f >> 7, colb = f & 127;
      int scol = colb ^ ((row & 7) << 4);
      load_lds16((const char*)(upd16 + (size_t)ridx[half][row] * 1024 + kk) + scol,
                 As + i * 4096 + w * 1024);
    }
    #pragma unroll
    for (int i = 0; i < 4; ++i) {        // stage B
      int f = i * 4096 + tid * 16;
      int row = f >> 7, colb = f & 127;
      int scol = colb ^ ((row & 7) << 4);
      load_lds16((const char*)(Wm + (size_t)(n0 + row) * 1024 + kk) + scol,
                 Bs + i * 4096 + w * 1024);
    }
    __syncthreads();
    #pragma unroll
    for (int ks = 0; ks < 2; ++ks) {
      s16x8 af[4], bfr[4];
      const int kb = ks * 64 + kq * 16;
      #pragma unroll
      for (int mi = 0; mi < 4; ++mi) {
        int row = wr + mi * 16 + r_lo;
        af[mi] = *(const s16x8*)(As + row * 128 + (kb ^ ((row & 7) << 4)));
      }
      #pragma unroll
      for (int ni = 0; ni < 4; ++ni) {
        int row = wc + ni * 16 + r_lo;
        bfr[ni] = *(const s16x8*)(Bs + row * 128 + (kb ^ ((row & 7) << 4)));
      }
      #pragma unroll
      for (int mi = 0; mi < 4; ++mi)
        #pragma unroll
        for (int ni = 0; ni < 4; ++ni)
          acc[mi][ni] = __builtin_amdgcn_mfma_f32_16x16x32_bf16(af[mi], bfr[ni], acc[mi][ni], 0, 0, 0);
    }
  }
  #pragma unroll
  for (int mi = 0; mi < 4; ++mi)
    #pragma unroll
    for (int ni = 0; ni < 4; ++ni)
      #pragma unroll
      for (int j = 0; j < 4; ++j) {
        int r = m0 + wr + mi * 16 + kq * 4 + j;
        int c = n0 + wc + ni * 16 + r_lo;
        C[(size_t)r * Hn + c] = acc[mi][ni][j] + C[(size_t)r * Hn + c];
      }
}

// ---------------------------------------------------------------------------
// MEGA: blocks 0..31 = GRU scan (MFMA matvec; tagged-payload exchange, no
// counter). Blocks 32..255 = worker pipeline: Ph0 wf/wih cvt; Ph1 gi GEMM +
// cnt (releases GRU); Ph2 scan + bulk cvts; Ph3 wl+pl; Ph4 scores+wfT;
// Ph5 softmax; Ph6 aw; Ph7 upd (dual write).
// ---------------------------------------------------------------------------
struct CvtTask { const float* src; u16* dst; int sld; int units; };
struct MKArgs {
  const float *w_hh_f, *w_hh_b, *b_hh_f, *b_hh_b;
  const float *word_feat, *w_ih_f, *w_ih_b, *b_ih_f, *b_ih_b;
  const float *phrase_feat, *w2p_w_b, *w2p_p_b, *w2p_t_b;
  const int *rcm, *conn;
  float *gi_f, *gi_b, *scores, *out_phr, *ctx;
  u16 *wf16, *wih16f, *wih16b, *wl;
  u16 *pf16, *w2pw16, *w2pp16, *w2pt16, *pl, *attw, *wfT, *aw, *upd16;
  u64* X; int* pc; int* cnt2; int* offs; int* cursor;
  CvtTask t[12]; int nt;
};

__global__ __launch_bounds__(256) void k_mega(MKArgs a)
{
  __shared__ __align__(16) u16 wlds[96 * 512];   // GRU weights / worker GEMM LDS
  __shared__ float bh[96];
  __shared__ float partg[4][96];
  __shared__ __align__(16) u16 hb[512];          // h as f16 bits

  const int bid = blockIdx.x;
  const int tid = threadIdx.x;
  const int lane = tid & 63, wv = tid >> 6;
  const int NW = (int)gridDim.x - 32;

  if (bid >= 32) {
    // =================== WORKER PATH ===================
    const int bc = bid - 32, nb = NW;
    int bar = 0;
    auto wbarrier = [&]() {
      __syncthreads();
      if (tid == 0) {
        __hip_atomic_fetch_add(&a.pc[bar], 1, __ATOMIC_ACQ_REL, __HIP_MEMORY_SCOPE_AGENT);
        while (__hip_atomic_load(&a.pc[bar], __ATOMIC_ACQUIRE, __HIP_MEMORY_SCOPE_AGENT) < NW)
          __builtin_amdgcn_s_sleep(4);
      }
      __syncthreads();
      ++bar;
    };
    auto cvt_task = [&](const float* src, int sld, u16* dst, int units) {
      for (int u = bc * 256 + tid; u < units; u += nb * 256) {
        int row = u >> 7, c = (u & 127) * 8;
        const float* s = src + (size_t)row * sld + c;
        float4 va = *(const float4*)s;
        float4 vb = *(const float4*)(s + 4);
        ushort4 lo = {f2b(va.x), f2b(va.y), f2b(va.z), f2b(va.w)};
        ushort4 hi = {f2b(vb.x), f2b(vb.y), f2b(vb.z), f2b(vb.w)};
        *(ushort4*)(dst + (size_t)row * 1024 + c) = lo;
        *(ushort4*)(dst + (size_t)row * 1024 + c + 4) = hi;
      }
    };

    // Ph0: word/w_ih conversions
    cvt_task(a.word_feat, Hn, a.wf16, Wn * 128);
    cvt_task(a.w_ih_f, Hn, a.wih16f, 1536 * 128);
    cvt_task(a.w_ih_b, Hn, a.wih16b, 1536 * 128);
    wbarrier();                                   // bar0
    // Ph1: gi GEMM tiles (24) + cnt histogram
    for (int u = bc; u < 24; u += nb) {
      const u16* Bm = u < 12 ? a.wih16f : a.wih16b;
      float* Cm = u < 12 ? a.gi_f : a.gi_b;
      const float* bm = u < 12 ? a.b_ih_f : a.b_ih_b;
      gemm_tile<true, false, true, false, false>((char*)wlds, a.wf16, Hn, Bm, Hn,
          Cm, 1536, bm, nullptr, 0, nullptr, 1.f, Hn, 0, (u % 12) * 128);
    }
    for (int u = bc * 256 + tid; u < 2 * Rn; u += nb * 256) {
      if (u < Rn && a.rcm[u] == a.rcm[Rn + u]) continue;
      atomicAdd(a.cnt2 + a.rcm[u], 1);
    }
    wbarrier();                                   // bar1 (releases GRU)
    // Ph2: scan (worker 0) + bulk conversions
    if (bc == 0) {
      int* part = (int*)wlds;
      int* pscan = part + 256;
      int loc[16]; int s = 0;
      #pragma unroll
      for (int i = 0; i < 16; ++i) { loc[i] = a.cnt2[tid * 16 + i]; s += loc[i]; }
      part[tid] = s; __syncthreads();
      if (tid == 0) { int acc = 0; for (int i = 0; i < 256; ++i) { pscan[i] = acc; acc += part[i]; } }
      __syncthreads();
      int base = pscan[tid];
      #pragma unroll
      for (int i = 0; i < 16; ++i) {
        a.offs[tid * 16 + i] = base; a.cursor[tid * 16 + i] = base; base += loc[i];
      }
      if (tid == 255) a.offs[Pn] = base;
      __syncthreads();
    }
    for (int k = 0; k < a.nt; ++k)
      cvt_task(a.t[k].src, a.t[k].sld, a.t[k].dst, a.t[k].units);
    wbarrier();                                   // bar2
    // Ph3: wl (8 tiles) + pl (256 tiles)
    for (int u = bc; u < 264; u += nb) {
      if (u < 8)
        gemm_tile<false, true, true, false, false>((char*)wlds, a.wf16, Hn,
            a.w2pw16, Hn, a.wl, Hn, a.w2p_w_b, nullptr, 0, nullptr, 1.f, Hn,
            0, u * 128);
      else {
        int t2 = u - 8;
        gemm_tile<false, true, true, false, false>((char*)wlds, a.pf16, Hn,
            a.w2pp16, Hn, a.pl, Hn, a.w2p_p_b, nullptr, 0, nullptr, 1.f, Hn,
            (t2 >> 3) * 128, (t2 & 7) * 128);
      }
    }
    wbarrier();                                   // bar3
    // Ph4: scores (32 tiles) + wfT transpose (512 units)
    for (int u = bc; u < 544; u += nb) {
      if (u < 32)
        gemm_tile<true, false, false, false, false>((char*)wlds, a.pl, Hn,
            a.wl, Hn, a.scores, Wn, nullptr, nullptr, 0, nullptr, 0.03125f, Hn,
            u * 128, 0);
      else {
        int idx = (u - 32) * 256 + tid;           // over 128*1024
        int r = idx >> 10, c = idx & 1023;
        a.wfT[c * 128 + r] = a.wf16[idx];
      }
    }
    wbarrier();                                   // bar4
    // Ph5: masked softmax (1024 units x 4 phrases)
    for (int u = bc; u < 1024; u += nb) {
      int p = u * 4 + wv;
      float v0 = a.scores[(size_t)p * 128 + lane];
      float v1 = a.scores[(size_t)p * 128 + 64 + lane];
      int m0 = a.conn[(size_t)p * 128 + lane];
      int m1 = a.conn[(size_t)p * 128 + 64 + lane];
      float x0 = m0 > 0 ? v0 : -INFINITY;
      float x1 = m1 > 0 ? v1 : -INFINITY;
      float mx = wred_max(fmaxf(x0, x1));
      if (!(mx > -INFINITY)) mx = 0.f;
      float e0 = m0 > 0 ? __expf(v0 - mx) : 0.f;
      float e1 = m1 > 0 ? __expf(v1 - mx) : 0.f;
      float s = wred_sum(e0 + e1);
      float inv = 1.f / (s + 1e-6f);
      a.attw[(size_t)p * 128 + lane] = f2b(e0 * inv);
      a.attw[(size_t)p * 128 + 64 + lane] = f2b(e1 * inv);
    }
    wbarrier();                                   // bar5
    // Ph6: aw = attw @ wfT^T (256 tiles, K=128)
    for (int u = bc; u < 256; u += nb)
      gemm_tile<false, false, false, false, false>((char*)wlds, a.attw, Wn,
          a.wfT, Wn, a.aw, Hn, nullptr, nullptr, 0, nullptr, 1.f, Wn,
          (u >> 3) * 128, (u & 7) * 128);
    wbarrier();                                   // bar6
    // Ph7: upd = phrase + aw @ w2p_t^T + b (f32 out_phr + bf16 upd16)
    for (int u = bc; u < 256; u += nb)
      gemm_tile<true, false, true, true, true>((char*)wlds, a.aw, Hn,
          a.w2pt16, Hn, a.out_phr, Hn, a.w2p_t_b, a.phrase_feat, Hn, a.upd16,
          1.f, Hn, (u >> 3) * 128, (u & 7) * 128);
    return;                                        // kernel end = final barrier
  }

  // =================== GRU PATH (blocks 0..31) ===================
  const int dir = bid >> 4;
  const int b   = bid & 15;
  const float* w_hh = dir ? a.w_hh_b : a.w_hh_f;
  const float* b_hhp = dir ? a.b_hh_b : a.b_hh_f;
  const float* gi = dir ? a.gi_b : a.gi_f;
  u64* Xd = a.X + (size_t)dir * 128 * 256;

  // weights f32 -> f16 LDS, row-major 1KB rows, byte ^ ((row&7)<<4) swizzle
  for (int idx = tid; idx < 96 * 128; idx += 256) {
    int gl = idx >> 7;
    int kc = (idx & 127) << 2;
    int g  = 32 * b + (gl & 31) + ((gl >> 5) << 9);
    float4 wv4 = *(const float4*)(w_hh + (size_t)g * 512 + kc);
    u16 d4[4] = {f2h(wv4.x), f2h(wv4.y), f2h(wv4.z), f2h(wv4.w)};
    int byte = (kc * 2) ^ ((gl & 7) << 4);
    *(uint2*)((char*)wlds + gl * 1024 + byte) = *(uint2*)d4;
  }
  if (tid < 96) {
    int g = 32 * b + (tid & 31) + ((tid >> 5) << 9);
    bh[tid] = b_hhp[g];
  }
  for (int i = tid; i < 256; i += 256) ((unsigned*)hb)[i] = 0u;
  // wait for gi (worker barrier index 1)
  if (tid == 0) {
    while (__hip_atomic_load(&a.pc[1], __ATOMIC_ACQUIRE, __HIP_MEMORY_SCOPE_AGENT) < NW)
      __builtin_amdgcn_s_sleep(16);
  }
  __syncthreads();

  float hprev = 0.f;
  const int jg = 32 * b + tid;          // tid<32 meaningful
  const int r_lo = lane & 15, kq = lane >> 4;
  const fp16x8 zf = {0, 0, 0, 0, 0, 0, 0, 0};

  for (int sidx = 0; sidx < 128; ++sidx) {
    const int t = dir ? (127 - sidx) : sidx;

    float gir = 0.f, giz = 0.f, gin = 0.f;
    if (tid < 32) {                     // prefetch under MFMA phase
      gir = gi[t * 1536 + jg];
      giz = gi[t * 1536 + 512 + jg];
      gin = gi[t * 1536 + 1024 + jg];
    }

    // MFMA matvec: wave wv covers K-tiles wv*4..wv*4+3, all 6 gate-tiles
    f32x4 acc6[6];
    #pragma unroll
    for (int gt = 0; gt < 6; ++gt) acc6[gt] = (f32x4){0.f, 0.f, 0.f, 0.f};
    #pragma unroll
    for (int k2 = 0; k2 < 4; ++k2) {
      int kt = (wv << 2) + k2;
      fp16x8 bf = (r_lo == 0) ? *(const fp16x8*)(hb + kt * 32 + kq * 8) : zf;
      #pragma unroll
      for (int gt = 0; gt < 6; ++gt) {
        int gl = gt * 16 + r_lo;
        int byte = (kt * 64 + kq * 16) ^ ((gl & 7) << 4);
        fp16x8 af = *(const fp16x8*)((const char*)wlds + gl * 1024 + byte);
        acc6[gt] = __builtin_amdgcn_mfma_f32_16x16x32_f16(af, bf, acc6[gt], 0, 0, 0);
      }
    }
    if (r_lo == 0) {                    // col-0 lanes: rows kq*4+j
      #pragma unroll
      for (int gt = 0; gt < 6; ++gt)
        #pragma unroll
        for (int j = 0; j < 4; ++j)
          partg[wv][gt * 16 + kq * 4 + j] = acc6[gt][j];
    }
    __syncthreads();

    if (wv == 0) {
      float h2v = 0.f;
      if (lane < 32) {
        int j = lane;
        float ghr = partg[0][j] + partg[1][j] + partg[2][j] + partg[3][j] + bh[j];
        float ghz = partg[0][j + 32] + partg[1][j + 32] + partg[2][j + 32] + partg[3][j + 32] + bh[j + 32];
        float ghn = partg[0][j + 64] + partg[1][j + 64] + partg[2][j + 64] + partg[3][j + 64] + bh[j + 64];
        float rr = 1.f / (1.f + __expf(-(gir + ghr)));
        float zz = 1.f / (1.f + __expf(-(giz + ghz)));
        float nn = tanhf(gin + rr * ghn);
        h2v = (1.f - zz) * nn + zz * hprev;
        hprev = h2v;
        if (sidx == 0)   a.ctx[(dir ? 1536 : 0)    + jg] = h2v;
        if (sidx == 127) a.ctx[(dir ? 512  : 1024) + jg] = h2v;
      }
      if (sidx < 127) {
        // tagged publish: 16 words/block, word = tag32<<32 | h1<<16 | h0
        float q0 = __shfl(h2v, (lane & 15) * 2, 64);
        float q1 = __shfl(h2v, (lane & 15) * 2 + 1, 64);
        if (lane < 16) {
          u64 pk = (u64)f2h(q0) | ((u64)f2h(q1) << 16) |
                   ((u64)(unsigned)(sidx + 1) << 32);
          __hip_atomic_store(&Xd[(size_t)sidx * 256 + b * 16 + lane], pk,
                             __ATOMIC_RELAXED, __HIP_MEMORY_SCOPE_AGENT);
        }
        // direct poll: 4 words/lane with done-mask (no counter round-trip)
        const u64* src = Xd + (size_t)sidx * 256;
        const unsigned want = (unsigned)(sidx + 1);
        const int base = lane * 4;
        u64 v[4];
        unsigned done = 0;
        while (done != 0xFu) {
          #pragma unroll
          for (int i = 0; i < 4; ++i)
            if (!(done & (1u << i)))
              v[i] = __hip_atomic_load(&src[base + i], __ATOMIC_RELAXED,
                                       __HIP_MEMORY_SCOPE_AGENT);
          #pragma unroll
          for (int i = 0; i < 4; ++i)
            if (!(done & (1u << i)) && (unsigned)(v[i] >> 32) == want)
              done |= 1u << i;
          if (done != 0xFu) __builtin_amdgcn_s_sleep(1);
        }
        #pragma unroll
        for (int i = 0; i < 4; ++i)
          ((unsigned*)hb)[base + i] = (unsigned)v[i];
      }
    }
    __syncthreads();                    // hb ready for all waves
  }
}

// ---------------------------------------------------------------------------
// tail kernels (ctx / urel dependent)
// ---------------------------------------------------------------------------
__global__ __launch_bounds__(256) void k_cvec(const float* __restrict__ att1W,
    const float* __restrict__ att1b, const float* __restrict__ ctx, float* __restrict__ cvec)
{
  int i = blockIdx.x * 4 + (threadIdx.x >> 6);
  int lane = threadIdx.x & 63;
  const float* wrow = att1W + (size_t)i * 4096 + 2048 + lane * 32;
  const float* cp = ctx + lane * 32;
  float acc = 0.f;
  #pragma unroll
  for (int k = 0; k < 32; ++k) acc += wrow[k] * cp[k];
  acc = wred_sum(acc);
  if (lane == 0) cvec[i] = acc + att1b[i];
}

__global__ __launch_bounds__(256) void k_edge_s(const int* __restrict__ rcm,
    const u16* __restrict__ U1, const u16* __restrict__ V1, const float* __restrict__ cvec,
    const float* __restrict__ att2w, const float* __restrict__ att2b,
    float* __restrict__ sval)
{
  int idx = blockIdx.x * 4 + (threadIdx.x >> 6);   // [0, 2*Rn)
  int lane = threadIdx.x & 63;
  int rL = idx < Rn ? idx : idx - Rn;
  int p = rcm[idx];
  const u16* u = U1 + (size_t)p * Hn + lane * 16;
  const u16* v = V1 + (size_t)rL * Hn + lane * 16;
  const float* aw = att2w + lane * 16;
  const float* cv = cvec + lane * 16;
  float acc = 0.f;
  #pragma unroll
  for (int i = 0; i < 16; ++i) {
    float x = b2f(u[i]) + b2f(v[i]) + cv[i];
    acc += aw[i] * leaky(x);
  }
  acc = wred_sum(acc);
  if (lane == 0) sval[idx] = acc + att2b[0];
}

__global__ __launch_bounds__(256) void k_fill(const int* __restrict__ rcm,
    const float* __restrict__ sval, int* __restrict__ cursor,
    int* __restrict__ er, float* __restrict__ es)
{
  int e = blockIdx.x * 256 + threadIdx.x;
  if (e < Rn && rcm[e] == rcm[Rn + e]) return;
  int slot = atomicAdd(cursor + rcm[e], 1);
  er[slot] = e & (Rn - 1);
  es[slot] = sval[e];
}

__global__ __launch_bounds__(256) void k_att_apply(const int* __restrict__ offs,
    const int* __restrict__ er, const float* __restrict__ es,
    const float* __restrict__ urel, u16* __restrict__ pacc)
{
  int p = blockIdx.x;
  int tid = threadIdx.x;
  int beg = offs[p], end = offs[p + 1];
  float mx = -INFINITY;
  for (int i = beg; i < end; ++i) mx = fmaxf(mx, es[i]);
  float den = 1e-6f;
  for (int i = beg; i < end; ++i) den += __expf(es[i] - mx);
  float inv = 1.f / den;
  float a0 = 0.f, a1 = 0.f, a2 = 0.f, a3 = 0.f;
  int c0 = tid * 4;
  for (int i = beg; i < end; ++i) {
    float wgt = __expf(es[i] - mx) * inv;
    float4 q = *(const float4*)(urel + (size_t)er[i] * Hn + c0);
    a0 += wgt * q.x; a1 += wgt * q.y; a2 += wgt * q.z; a3 += wgt * q.w;
  }
  ushort4 ov; ov.x = f2b(a0); ov.y = f2b(a1); ov.z = f2b(a2); ov.w = f2b(a3);
  *(ushort4*)(pacc + (size_t)p * Hn + c0) = ov;
}

// ---------------------------------------------------------------------------
extern "C" void kernel_launch(void* const* d_in, const int* in_sizes, int n_in,
                              void* d_out, int out_size, void* d_ws, size_t ws_size,
                              hipStream_t stream)
{
  const float* word_feat   = (const float*)d_in[0];
  const float* phrase_feat = (const float*)d_in[1];
  const float* rel_feat    = (const float*)d_in[2];
  const float* w_ih_f = (const float*)d_in[3];
  const float* w_hh_f = (const float*)d_in[4];
  const float* b_ih_f = (const float*)d_in[5];
  const float* b_hh_f = (const float*)d_in[6];
  const float* w_ih_b = (const float*)d_in[7];
  const float* w_hh_b = (const float*)d_in[8];
  const float* b_ih_b = (const float*)d_in[9];
  const float* b_hh_b = (const float*)d_in[10];
  const float* w2p_w_W = (const float*)d_in[11];
  const float* w2p_w_b = (const float*)d_in[12];
  const float* w2p_p_W = (const float*)d_in[13];
  const float* w2p_p_b = (const float*)d_in[14];
  const float* w2p_t_W = (const float*)d_in[15];
  const float* w2p_t_b = (const float*)d_in[16];
  const float* rel_W   = (const float*)d_in[17];
  const float* rel_b   = (const float*)d_in[18];
  const float* att1_W  = (const float*)d_in[19];
  const float* att1_b  = (const float*)d_in[20];
  const float* att2_W  = (const float*)d_in[21];
  const float* att2_b  = (const float*)d_in[22];
  const float* r2p_t_W = (const float*)d_in[23];
  const float* r2p_t_b = (const float*)d_in[24];
  const int* rcm  = (const int*)d_in[25];
  const int* conn = (const int*)d_in[26];

  float* out_word = (float*)d_out;
  float* out_phr  = out_word + (size_t)Wn * Hn;   // 4096x1024 f32
  float* out_urel = out_phr + (size_t)Pn * Hn;    // 8192x1024 f32

  // ---- workspace (~44 MB, proven layout) ----
  char* ws = (char*)d_ws;
  size_t off = 0;
  auto alloc = [&](size_t bytes) -> char* {
    char* pptr = ws + off; off += (bytes + 255) & ~(size_t)255; return pptr;
  };
  int*   cnt2   = (int*)alloc(Pn * 4);                    // } zeroed together
  int*   pc     = (int*)alloc(64 * 4);                    // }
  u64*   X      = (u64*)alloc(2 * 128 * 256 * 8);         // } 512KB tagged h
  size_t zlen   = (size_t)((char*)(X + 2 * 128 * 256) - (char*)cnt2);
  float* ctx    = (float*)alloc(2048 * 4);
  float* cvec   = (float*)alloc(1024 * 4);
  int*   cursor = (int*)alloc(Pn * 4);
  int*   offs   = (int*)alloc((Pn + 1) * 4);
  int*   er     = (int*)alloc(2 * Rn * 4);
  float* es     = (float*)alloc(2 * Rn * 4);
  float* sval   = (float*)alloc(2 * Rn * 4);
  float* gi_f   = (float*)alloc(128 * 1536 * 4);
  float* gi_b   = (float*)alloc(128 * 1536 * 4);
  u16*   wf16   = (u16*)alloc((size_t)Wn * Hn * 2);
  u16*   wl     = (u16*)alloc((size_t)Wn * Hn * 2);
  u16*   upd16  = (u16*)alloc((size_t)Pn * Hn * 2);       // later: pacc
  char*  RA     = alloc(16777216);                        // W1s/W2s/W3s/G -> V1f
  u16*   W1s    = (u16*)RA;
  u16*   W2s    = (u16*)(RA + 2097152);
  u16*   W3s    = (u16*)(RA + 4194304);
  u16*   G      = (u16*)(RA + 6291456);                   // 8.39MB (rel lower)
  u16*   V1f    = (u16*)RA;                               // 16.78MB (late)
  u16*   A1p16  = (u16*)alloc(2097152);
  u16*   A1r16  = (u16*)alloc(2097152);
  u16*   U1     = (u16*)alloc((size_t)Pn * Hn * 2);       // relU16 early, U1 late
  u16*   relU16 = U1;                                     // rel upper bf16 (dies at rf3)
  u16*   r2pW16 = (u16*)alloc(2097152);
  u16*   pacc   = upd16;                                  // after U1 GEMM done

  // ---- d_out regions as early scratch ----
  char* phrB = (char*)out_phr;
  u16*   wih16f = (u16*)phrB;                           // 3.15MB (dies after gi)
  u16*   wih16b = (u16*)(phrB + 3145728);               // 3.15MB
  float* scores = (float*)(phrB + 6291456);             // 2.10MB (dies Ph5)
  char* urlB = (char*)out_urel;
  u16*   pf16   = (u16*)urlB;                           // 8.39MB
  u16*   w2pw16 = (u16*)(urlB + 8388608);
  u16*   w2pp16 = (u16*)(urlB + 10485760);
  u16*   w2pt16 = (u16*)(urlB + 12582912);
  u16*   pl     = (u16*)(urlB + 14680064);              // 8.39MB
  u16*   aw     = (u16*)(urlB + 23068672);              // 8.39MB
  u16*   attw   = (u16*)(urlB + 31457280);              // 1.05MB
  u16*   wfT    = (u16*)(urlB + 32505856);              // 0.26MB

  (void)hipMemsetAsync(cnt2, 0, zlen, stream);

  dim3 blk(256);

  // mega: GRU || {cvts -> gi+cnt -> scan+cvts -> w2p chain through upd}
  MKArgs A;
  A.w_hh_f = w_hh_f; A.w_hh_b = w_hh_b; A.b_hh_f = b_hh_f; A.b_hh_b = b_hh_b;
  A.word_feat = word_feat; A.w_ih_f = w_ih_f; A.w_ih_b = w_ih_b;
  A.b_ih_f = b_ih_f; A.b_ih_b = b_ih_b;
  A.phrase_feat = phrase_feat; A.w2p_w_b = w2p_w_b; A.w2p_p_b = w2p_p_b;
  A.w2p_t_b = w2p_t_b; A.rcm = rcm; A.conn = conn;
  A.gi_f = gi_f; A.gi_b = gi_b; A.scores = scores; A.out_phr = out_phr; A.ctx = ctx;
  A.wf16 = wf16; A.wih16f = wih16f; A.wih16b = wih16b; A.wl = wl;
  A.pf16 = pf16; A.w2pw16 = w2pw16; A.w2pp16 = w2pp16; A.w2pt16 = w2pt16;
  A.pl = pl; A.attw = attw; A.wfT = wfT; A.aw = aw; A.upd16 = upd16;
  A.X = X; A.pc = pc; A.cnt2 = cnt2; A.offs = offs; A.cursor = cursor;
  A.t[0]  = {phrase_feat,    pf16,   Hn,     Pn * 128};
  A.t[1]  = {w2p_w_W,        w2pw16, Hn,     1024 * 128};
  A.t[2]  = {w2p_p_W,        w2pp16, Hn,     1024 * 128};
  A.t[3]  = {w2p_t_W,        w2pt16, Hn,     1024 * 128};
  A.t[4]  = {rel_W,          W1s,    3 * Hn, 1024 * 128};
  A.t[5]  = {rel_W + Hn,     W2s,    3 * Hn, 1024 * 128};
  A.t[6]  = {rel_W + 2 * Hn, W3s,    3 * Hn, 1024 * 128};
  A.t[7]  = {att1_W,         A1p16,  4 * Hn, 1024 * 128};
  A.t[8]  = {att1_W + Hn,    A1r16,  4 * Hn, 1024 * 128};
  A.t[9]  = {r2p_t_W,        r2pW16, Hn,     1024 * 128};
  A.t[10] = {rel_feat,       G,      Hn,     4096 * 128};            // rel lower
  A.t[11] = {rel_feat + (size_t)4096 * Hn, relU16, Hn, 4096 * 128};  // rel upper
  A.nt = 12;
  k_mega<<<256, blk, 0, stream>>>(A);
  k_cvec<<<256, blk, 0, stream>>>(att1_W, att1_b, ctx, cvec);

  // urel: batched RF3 (both halves), then batched dual-gather accumulate
  k_rf3<<<dim3(8, 64), blk, 0, stream>>>(G, relU16, W3s, rel_b, out_urel);
  k_gemm_rel<<<dim3(8, 64), blk, 0, stream>>>(upd16, rcm, W1s, W2s, out_urel);

  // U1 (writes over dead relU16), then V1 directly from f32 urel
  k_gemm_bt<false, false, false, false, false><<<dim3(8, 32), blk, 0, stream>>>(
      upd16, Hn, A1p16, Hn, U1, Hn, nullptr, nullptr, 0, nullptr, 1.f, Hn);
  k_gemm_af32<<<dim3(8, 64), blk, 0, stream>>>(
      out_urel, Hn, A1r16, Hn, V1f, Hn, Hn);

  // edge scores + CSR softmax + att@urel + final residual GEMM
  k_edge_s<<<(2 * Rn) / 4, blk, 0, stream>>>(rcm, U1, V1f, cvec, att2_W, att2_b, sval);
  k_fill<<<(2 * Rn) / 256, blk, 0, stream>>>(rcm, sval, cursor, er, es);
  k_att_apply<<<Pn, blk, 0, stream>>>(offs, er, es, out_urel, pacc);
  k_gemm_bt<true, false, true, true, false><<<dim3(8, 32), blk, 0, stream>>>(
      pacc, Hn, r2pW16, Hn, out_phr, Hn, r2p_t_b, out_phr, Hn, nullptr, 1.f, Hn);

  (void)hipMemcpyAsync(out_word, word_feat, (size_t)Wn * Hn * 4,
                       hipMemcpyDeviceToDevice, stream);
}